// Round 1
// 749.895 us; speedup vs baseline: 1.7628x; 1.7628x over previous
//
#include <hip/hip_runtime.h>
#include <stdint.h>
#include <math.h>

#define DIM 4096
#define NH 32
#define NKV 8
#define HD 128
#define SEQ 2048
#define KVDIM (NKV * HD)   // 1024

typedef __bf16 bf16x8 __attribute__((ext_vector_type(8)));
typedef float floatx4 __attribute__((ext_vector_type(4)));
typedef uint16_t u16x8 __attribute__((ext_vector_type(8)));

#define AS1C(p) ((const __attribute__((address_space(1))) void*)(p))
#define AS3(p)  ((__attribute__((address_space(3))) void*)(p))

__device__ __forceinline__ float b2f(uint16_t u) {
    union { uint32_t i; float f; } v; v.i = ((uint32_t)u) << 16; return v.f;
}
__device__ __forceinline__ uint16_t f2b(float f) {
    union { float f; uint32_t i; } v; v.f = f;
    uint32_t r = v.i + 0x7fffu + ((v.i >> 16) & 1u);   // RTNE
    return (uint16_t)(r >> 16);
}

// Load 8 logical bf16 elements starting at element index e of buffer p,
// where p is bf16 (isf32=false) or f32 (isf32=true; convert to bf16).
__device__ __forceinline__ u16x8 ldchunk(const void* p, bool isf32, size_t e) {
    if (isf32) {
        const float* fp = (const float*)p + e;
        u16x8 r;
#pragma unroll
        for (int j = 0; j < 8; ++j) r[j] = f2b(fp[j]);
        return r;
    }
    return *(const u16x8*)((const uint16_t*)p + e);
}

// ---------------------------------------------------------------------------
// dtype detector: interpret first 4096 elements of x as bf16. True bf16
// N(0,1) data -> 0 "bad"; f32 data misread as bf16 -> ~40% bad.
// flag: 0 = bf16 inputs, 1 = f32 inputs.
// ---------------------------------------------------------------------------
__global__ void detect_k(const uint16_t* __restrict__ x, int* __restrict__ flag) {
    __shared__ int cnt;
    if (threadIdx.x == 0) cnt = 0;
    __syncthreads();
    int bad = 0;
    for (int i = threadIdx.x; i < 4096; i += 256) {
        float v = b2f(x[i]);
        if (!(fabsf(v) < 1e6f)) bad++;   // NaN compares false -> counted
    }
    atomicAdd(&cnt, bad);
    __syncthreads();
    if (threadIdx.x == 0) *flag = (cnt > 256) ? 1 : 0;
}

// ---------------------------------------------------------------------------
// convert kernel: f32 -> bf16 (flag==1) or bf16 copy (flag==0). n % 8 == 0.
// ---------------------------------------------------------------------------
__global__ __launch_bounds__(256) void conv_k(const void* __restrict__ src,
                                              uint16_t* __restrict__ dst,
                                              size_t n,
                                              const int* __restrict__ flagp) {
    const int f = *flagp;
    size_t i = ((size_t)blockIdx.x * blockDim.x + threadIdx.x) * 8;
    const size_t stride = (size_t)gridDim.x * blockDim.x * 8;
    if (f) {
        for (; i < n; i += stride) {
            const float* s = (const float*)src + i;
            u16x8 r;
#pragma unroll
            for (int j = 0; j < 8; ++j) r[j] = f2b(s[j]);
            *(u16x8*)(dst + i) = r;
        }
    } else {
        for (; i < n; i += stride)
            *(u16x8*)(dst + i) = *(const u16x8*)((const uint16_t*)src + i);
    }
}

// ---------------------------------------------------------------------------
// Legacy NT GEMM (fallback when workspace too small): dynamic dtype operands.
// ---------------------------------------------------------------------------
__global__ __launch_bounds__(256) void gemm_nt(const void* __restrict__ A,
                                               const void* __restrict__ B,
                                               void* __restrict__ C,
                                               int K, int ldc,
                                               const int* __restrict__ flagp,
                                               int a_dyn, int b_dyn, int out_dyn) {
    __shared__ uint16_t As[128 * 64];
    __shared__ uint16_t Bs[128 * 64];
    const int f = *flagp;
    const bool af32 = a_dyn && f, bf32 = b_dyn && f, of32 = out_dyn && f;
    const int tid = threadIdx.x;
    const int wave = tid >> 6, lane = tid & 63;
    const int wh = wave >> 1, ww = wave & 1;
    const int quad = lane >> 4, l16 = lane & 15;
    const int m0 = blockIdx.x * 128;
    const int n0 = blockIdx.y * 128;

    floatx4 acc[4][4] = {};

    for (int k0 = 0; k0 < K; k0 += 64) {
        __syncthreads();
#pragma unroll
        for (int it = 0; it < 4; ++it) {
            int id = tid + it * 256;
            int row = id >> 3, slot = id & 7;
            int c8 = ((slot ^ (row & 7)) << 3);
            u16x8 va = ldchunk(A, af32, (size_t)(m0 + row) * K + k0 + c8);
            *(u16x8*)(As + row * 64 + slot * 8) = va;
            u16x8 vb = ldchunk(B, bf32, (size_t)(n0 + row) * K + k0 + c8);
            *(u16x8*)(Bs + row * 64 + slot * 8) = vb;
        }
        __syncthreads();
#pragma unroll
        for (int ks = 0; ks < 2; ++ks) {
            bf16x8 af[4], bf[4];
#pragma unroll
            for (int mi = 0; mi < 4; ++mi) {
                int r = wh * 64 + mi * 16 + l16;
                int slot = (ks * 4 + quad) ^ (r & 7);
                af[mi] = *(const bf16x8*)(As + r * 64 + slot * 8);
            }
#pragma unroll
            for (int ni = 0; ni < 4; ++ni) {
                int r = ww * 64 + ni * 16 + l16;
                int slot = (ks * 4 + quad) ^ (r & 7);
                bf[ni] = *(const bf16x8*)(Bs + r * 64 + slot * 8);
            }
#pragma unroll
            for (int mi = 0; mi < 4; ++mi)
#pragma unroll
                for (int ni = 0; ni < 4; ++ni)
                    acc[mi][ni] = __builtin_amdgcn_mfma_f32_16x16x32_bf16(
                        af[mi], bf[ni], acc[mi][ni], 0, 0, 0);
        }
    }
#pragma unroll
    for (int mi = 0; mi < 4; ++mi) {
#pragma unroll
        for (int ni = 0; ni < 4; ++ni) {
            int row = m0 + wh * 64 + mi * 16 + quad * 4;
            int col = n0 + ww * 64 + ni * 16 + l16;
            if (of32) {
#pragma unroll
                for (int i = 0; i < 4; ++i)
                    ((float*)C)[(size_t)(row + i) * ldc + col] = acc[mi][ni][i];
            } else {
#pragma unroll
                for (int i = 0; i < 4; ++i)
                    ((uint16_t*)C)[(size_t)(row + i) * ldc + col] = f2b(acc[mi][ni][i]);
            }
        }
    }
}

// ---------------------------------------------------------------------------
// Fast NT GEMM: pure bf16 operands, global_load_lds(16B) staging.
// LDS layout identical to legacy (XOR-swizzled slots); swizzle applied to the
// per-lane GLOBAL source address, LDS destination is linear (rule #21).
// C[m][n] = sum_k A[m][k]*B[n][k]. BM=BN=128, BK=64, 256 thr (2x2 waves).
// ---------------------------------------------------------------------------
__global__ __launch_bounds__(256) void gemm_bf(const uint16_t* __restrict__ A,
                                               const uint16_t* __restrict__ B,
                                               void* __restrict__ C,
                                               int K, int ldc,
                                               const int* __restrict__ flagp,
                                               int out_dyn) {
    __shared__ uint16_t As[128 * 64];
    __shared__ uint16_t Bs[128 * 64];
    const bool of32 = out_dyn && (*flagp);
    const int tid = threadIdx.x;
    const int wave = tid >> 6, lane = tid & 63;
    const int wh = wave >> 1, ww = wave & 1;
    const int quad = lane >> 4, l16 = lane & 15;
    const int m0 = blockIdx.x * 128;
    const int n0 = blockIdx.y * 128;

    floatx4 acc[4][4] = {};

    for (int k0 = 0; k0 < K; k0 += 64) {
        __syncthreads();   // prior iteration's LDS reads done
#pragma unroll
        for (int it = 0; it < 4; ++it) {
            int id = tid + it * 256;          // chunk id 0..1023
            int row = id >> 3, slot = id & 7;
            int c8 = ((slot ^ (row & 7)) << 3);
            // LDS dest: linear chunk order (wave-uniform base + lane*16B)
            __builtin_amdgcn_global_load_lds(
                AS1C(A + (size_t)(m0 + row) * K + k0 + c8),
                AS3(As + (size_t)(it * 256 + wave * 64) * 8), 16, 0, 0);
            __builtin_amdgcn_global_load_lds(
                AS1C(B + (size_t)(n0 + row) * K + k0 + c8),
                AS3(Bs + (size_t)(it * 256 + wave * 64) * 8), 16, 0, 0);
        }
        __syncthreads();   // vmcnt(0) drain + barrier: tiles visible
#pragma unroll
        for (int ks = 0; ks < 2; ++ks) {
            bf16x8 af[4], bf[4];
#pragma unroll
            for (int mi = 0; mi < 4; ++mi) {
                int r = wh * 64 + mi * 16 + l16;
                int slot = (ks * 4 + quad) ^ (r & 7);
                af[mi] = *(const bf16x8*)(As + r * 64 + slot * 8);
            }
#pragma unroll
            for (int ni = 0; ni < 4; ++ni) {
                int r = ww * 64 + ni * 16 + l16;
                int slot = (ks * 4 + quad) ^ (r & 7);
                bf[ni] = *(const bf16x8*)(Bs + r * 64 + slot * 8);
            }
#pragma unroll
            for (int mi = 0; mi < 4; ++mi)
#pragma unroll
                for (int ni = 0; ni < 4; ++ni)
                    acc[mi][ni] = __builtin_amdgcn_mfma_f32_16x16x32_bf16(
                        af[mi], bf[ni], acc[mi][ni], 0, 0, 0);
        }
    }
    // epilogue: C/D layout row = quad*4 + i, col = lane&15
#pragma unroll
    for (int mi = 0; mi < 4; ++mi) {
#pragma unroll
        for (int ni = 0; ni < 4; ++ni) {
            int row = m0 + wh * 64 + mi * 16 + quad * 4;
            int col = n0 + ww * 64 + ni * 16 + l16;
            if (of32) {
#pragma unroll
                for (int i = 0; i < 4; ++i)
                    ((float*)C)[(size_t)(row + i) * ldc + col] = acc[mi][ni][i];
            } else {
#pragma unroll
                for (int i = 0; i < 4; ++i)
                    ((uint16_t*)C)[(size_t)(row + i) * ldc + col] = f2b(acc[mi][ni][i]);
            }
        }
    }
}

// ---------------------------------------------------------------------------
// RoPE in-place on [SEQ][heads*HD] bf16 buffer (interleaved even/odd pairs)
// ---------------------------------------------------------------------------
__global__ void rope_k(uint16_t* __restrict__ buf, int heads) {
    int id = blockIdx.x * blockDim.x + threadIdx.x;
    int i = id & 63;
    int h = (id >> 6) % heads;
    int t = id / (64 * heads);
    uint16_t* p = buf + (size_t)t * (heads * HD) + h * HD + 2 * i;
    float e = b2f(p[0]), o = b2f(p[1]);
    float freq = exp2f(-(float)(2 * i) * (18.93156857f / 128.0f));
    float ang = (float)t * freq;
    float s, c;
    sincosf(ang, &s, &c);
    p[0] = f2b(e * c - o * s);
    p[1] = f2b(e * s + o * c);
}

// ---------------------------------------------------------------------------
// Flash attention (causal, GQA rep=4). One block = (head, 128-q-row tile).
// 256 threads, waves 2x2. Q/K staged via global_load_lds (swizzled global
// source, linear LDS dest). V transposed via register scatter (unchanged).
// ---------------------------------------------------------------------------
__global__ __launch_bounds__(256, 1) void attn_k(const uint16_t* __restrict__ Q,
                                                 const uint16_t* __restrict__ Kg,
                                                 const uint16_t* __restrict__ Vg,
                                                 uint16_t* __restrict__ O) {
    __shared__ uint16_t Qs[128 * 128];
    __shared__ uint16_t Ks[128 * 128];
    __shared__ uint16_t Vt[128 * 128];
    __shared__ float redm[2][128];
    __shared__ float reds[2][128];

    const int tid = threadIdx.x;
    const int wave = tid >> 6, lane = tid & 63;
    const int wh = wave >> 1, ww = wave & 1;
    const int quad = lane >> 4, l16 = lane & 15;

    const int qt = 15 - (blockIdx.x >> 5);   // heavy q-tiles first
    const int h = blockIdx.x & 31;
    const int kvh = h >> 2;
    const int q0 = qt * 128;

    // stage Q tile via global_load_lds (drains at first in-loop barrier)
#pragma unroll
    for (int it = 0; it < 8; ++it) {
        int id = tid + it * 256;
        int row = id >> 4, slot = id & 15;
        int c8 = ((slot ^ (row & 7)) << 3);
        __builtin_amdgcn_global_load_lds(
            AS1C(Q + (size_t)(q0 + row) * DIM + h * HD + c8),
            AS3(Qs + (size_t)(it * 256 + wave * 64) * 8), 16, 0, 0);
    }

    floatx4 acc_o[4][4] = {};
    float m_run[4][4], l_run[4][4];
#pragma unroll
    for (int mi = 0; mi < 4; ++mi)
#pragma unroll
        for (int i = 0; i < 4; ++i) { m_run[mi][i] = -__builtin_inff(); l_run[mi][i] = 0.f; }

    const float scale = 0.08838834764831845f;  // 1/sqrt(128)
    const float LOG2E = 1.44269504f;

    for (int kt = 0; kt <= qt; ++kt) {
        const int k0 = kt * 128;
        __syncthreads();   // prior tile's P/Vt reads done; Q loads drained
        // stage K tile via global_load_lds
#pragma unroll
        for (int it = 0; it < 8; ++it) {
            int id = tid + it * 256;
            int row = id >> 4, slot = id & 15;
            int c8 = ((slot ^ (row & 7)) << 3);
            __builtin_amdgcn_global_load_lds(
                AS1C(Kg + (size_t)(k0 + row) * KVDIM + kvh * HD + c8),
                AS3(Ks + (size_t)(it * 256 + wave * 64) * 8), 16, 0, 0);
        }
        // stage V transposed: Vt[d][key], key-chunk slot swizzled with (d&7)
        {
            int key = tid & 127;
            int dhalf = tid >> 7;
#pragma unroll
            for (int it = 0; it < 8; ++it) {
                int dc = it * 2 + dhalf;
                u16x8 v = *(const u16x8*)(Vg + (size_t)(k0 + key) * KVDIM + kvh * HD + dc * 8);
#pragma unroll
                for (int j = 0; j < 8; ++j) {
                    int d = dc * 8 + j;
                    Vt[d * 128 + (((key >> 3) ^ (d & 7)) << 3) + (key & 7)] = v[j];
                }
            }
        }
        __syncthreads();   // staging visible

        // S = Q K^T
        floatx4 acc_s[4][4] = {};
#pragma unroll
        for (int ks = 0; ks < 4; ++ks) {
            bf16x8 qf[4], kf[4];
#pragma unroll
            for (int mi = 0; mi < 4; ++mi) {
                int r = wh * 64 + mi * 16 + l16;
                int slot = (ks * 4 + quad) ^ (r & 7);
                qf[mi] = *(const bf16x8*)(Qs + r * 128 + slot * 8);
            }
#pragma unroll
            for (int ni = 0; ni < 4; ++ni) {
                int r = ww * 64 + ni * 16 + l16;
                int slot = (ks * 4 + quad) ^ (r & 7);
                kf[ni] = *(const bf16x8*)(Ks + r * 128 + slot * 8);
            }
#pragma unroll
            for (int mi = 0; mi < 4; ++mi)
#pragma unroll
                for (int ni = 0; ni < 4; ++ni)
                    acc_s[mi][ni] = __builtin_amdgcn_mfma_f32_16x16x32_bf16(
                        qf[mi], kf[ni], acc_s[mi][ni], 0, 0, 0);
        }

        // scale + causal mask
#pragma unroll
        for (int mi = 0; mi < 4; ++mi)
#pragma unroll
            for (int ni = 0; ni < 4; ++ni)
#pragma unroll
                for (int i = 0; i < 4; ++i) {
                    float s = acc_s[mi][ni][i] * scale;
                    if (kt == qt) {
                        int ql = wh * 64 + mi * 16 + quad * 4 + i;
                        int kl = ww * 64 + ni * 16 + l16;
                        if (kl > ql) s = -__builtin_inff();
                    }
                    acc_s[mi][ni][i] = s;
                }

        // wave-local row max -> cross-wave via LDS
#pragma unroll
        for (int mi = 0; mi < 4; ++mi)
#pragma unroll
            for (int i = 0; i < 4; ++i) {
                float v = fmaxf(fmaxf(acc_s[mi][0][i], acc_s[mi][1][i]),
                                fmaxf(acc_s[mi][2][i], acc_s[mi][3][i]));
#pragma unroll
                for (int off = 1; off < 16; off <<= 1)
                    v = fmaxf(v, __shfl_xor(v, off));
                if (l16 == 0) redm[ww][wh * 64 + mi * 16 + quad * 4 + i] = v;
            }
        __syncthreads();   // redm visible; all Ks reads done -> safe to write P

        float alpha[4][4], mnew[4][4];
#pragma unroll
        for (int mi = 0; mi < 4; ++mi)
#pragma unroll
            for (int i = 0; i < 4; ++i) {
                int row = wh * 64 + mi * 16 + quad * 4 + i;
                float tm = fmaxf(redm[0][row], redm[1][row]);
                float mn = fmaxf(m_run[mi][i], tm);
                alpha[mi][i] = exp2f((m_run[mi][i] - mn) * LOG2E);
                mnew[mi][i] = mn;
            }

        // p = exp(s - m) -> bf16 P into Ks; row sums
#pragma unroll
        for (int mi = 0; mi < 4; ++mi)
#pragma unroll
            for (int i = 0; i < 4; ++i) {
                int ql = wh * 64 + mi * 16 + quad * 4 + i;
                float sum = 0.f;
#pragma unroll
                for (int ni = 0; ni < 4; ++ni) {
                    float p = exp2f((acc_s[mi][ni][i] - mnew[mi][i]) * LOG2E);
                    sum += p;
                    int key = ww * 64 + ni * 16 + l16;
                    Ks[ql * 128 + (((key >> 3) ^ (ql & 7)) << 3) + (key & 7)] = f2b(p);
                }
#pragma unroll
                for (int off = 1; off < 16; off <<= 1)
                    sum += __shfl_xor(sum, off);
                if (l16 == 0) reds[ww][ql] = sum;
            }
        __syncthreads();   // P + sums visible

#pragma unroll
        for (int mi = 0; mi < 4; ++mi)
#pragma unroll
            for (int i = 0; i < 4; ++i) {
                int row = wh * 64 + mi * 16 + quad * 4 + i;
                l_run[mi][i] = l_run[mi][i] * alpha[mi][i] + reds[0][row] + reds[1][row];
                m_run[mi][i] = mnew[mi][i];
            }
#pragma unroll
        for (int mi = 0; mi < 4; ++mi)
#pragma unroll
            for (int ni = 0; ni < 4; ++ni)
#pragma unroll
                for (int i = 0; i < 4; ++i)
                    acc_o[mi][ni][i] *= alpha[mi][i];

        // O += P V ; P in Ks (A-operand), V^T in Vt (B-operand)
#pragma unroll
        for (int ks = 0; ks < 4; ++ks) {
            bf16x8 pf[4], vf[4];
#pragma unroll
            for (int mi = 0; mi < 4; ++mi) {
                int r = wh * 64 + mi * 16 + l16;
                int slot = (ks * 4 + quad) ^ (r & 7);
                pf[mi] = *(const bf16x8*)(Ks + r * 128 + slot * 8);
            }
#pragma unroll
            for (int ni = 0; ni < 4; ++ni) {
                int d = ww * 64 + ni * 16 + l16;
                int slot = (ks * 4 + quad) ^ (d & 7);
                vf[ni] = *(const bf16x8*)(Vt + d * 128 + slot * 8);
            }
#pragma unroll
            for (int mi = 0; mi < 4; ++mi)
#pragma unroll
                for (int ni = 0; ni < 4; ++ni)
                    acc_o[mi][ni] = __builtin_amdgcn_mfma_f32_16x16x32_bf16(
                        pf[mi], vf[ni], acc_o[mi][ni], 0, 0, 0);
        }
    }

    // epilogue
#pragma unroll
    for (int mi = 0; mi < 4; ++mi)
#pragma unroll
        for (int i = 0; i < 4; ++i) {
            float inv = 1.0f / l_run[mi][i];
            int row = q0 + wh * 64 + mi * 16 + quad * 4 + i;
#pragma unroll
            for (int ni = 0; ni < 4; ++ni) {
                int col = h * HD + ww * 64 + ni * 16 + l16;
                O[(size_t)row * DIM + col] = f2b(acc_o[mi][ni][i] * inv);
            }
        }
}

extern "C" void kernel_launch(void* const* d_in, const int* in_sizes, int n_in,
                              void* d_out, int out_size, void* d_ws, size_t ws_size,
                              hipStream_t stream) {
    const void* x  = d_in[0];
    const void* wq = d_in[1];
    const void* wk = d_in[2];
    const void* wv = d_in[3];
    const void* wo = d_in[4];

    // ws layout: [flag 256B][Kb 4.2MB][Vb 4.2MB][Ab 16.8MB]
    // fast path adds: [xb 16.8MB][W1 33.6MB (wq->wo)][W2 8.4MB (wk->wv)]
    int* flag = (int*)d_ws;
    uint16_t* Kb = (uint16_t*)((char*)d_ws + 256);
    uint16_t* Vb = Kb + (size_t)SEQ * KVDIM;
    uint16_t* Ab = Vb + (size_t)SEQ * KVDIM;
    // Q lives in d_out (dead before the final GEMM overwrites d_out)
    uint16_t* Qb = (uint16_t*)d_out;

    const size_t fixed = 256 + 2 * (size_t)SEQ * KVDIM * 2 + (size_t)SEQ * DIM * 2;
    const size_t extra = (size_t)SEQ * DIM * 2      // xb
                       + (size_t)DIM * DIM * 2      // W1
                       + (size_t)KVDIM * DIM * 2;   // W2

    dim3 blk(256);
    detect_k<<<1, blk, 0, stream>>>((const uint16_t*)x, flag);

    if (ws_size >= fixed + extra) {
        // fast path: pre-convert to bf16, global_load_lds GEMMs
        uint16_t* xb = Ab + (size_t)SEQ * DIM;
        uint16_t* W1 = xb + (size_t)SEQ * DIM;
        uint16_t* W2 = W1 + (size_t)DIM * DIM;

        conv_k<<<2048, blk, 0, stream>>>(x, xb, (size_t)SEQ * DIM, flag);
        conv_k<<<2048, blk, 0, stream>>>(wq, W1, (size_t)DIM * DIM, flag);
        gemm_bf<<<dim3(SEQ / 128, DIM / 128), blk, 0, stream>>>(xb, W1, Qb, DIM, DIM, flag, 0);
        conv_k<<<2048, blk, 0, stream>>>(wk, W2, (size_t)KVDIM * DIM, flag);
        gemm_bf<<<dim3(SEQ / 128, KVDIM / 128), blk, 0, stream>>>(xb, W2, Kb, DIM, KVDIM, flag, 0);
        conv_k<<<2048, blk, 0, stream>>>(wv, W2, (size_t)KVDIM * DIM, flag);   // W2 free after wk GEMM (stream order)
        gemm_bf<<<dim3(SEQ / 128, KVDIM / 128), blk, 0, stream>>>(xb, W2, Vb, DIM, KVDIM, flag, 0);
        rope_k<<<(SEQ * NH * 64) / 256, 256, 0, stream>>>(Qb, NH);
        rope_k<<<(SEQ * NKV * 64) / 256, 256, 0, stream>>>(Kb, NKV);
        attn_k<<<NH * (SEQ / 128), blk, 0, stream>>>(Qb, Kb, Vb, Ab);
        conv_k<<<2048, blk, 0, stream>>>(wo, W1, (size_t)DIM * DIM, flag);     // W1 free after wq GEMM
        gemm_bf<<<dim3(SEQ / 128, DIM / 128), blk, 0, stream>>>(Ab, W1, d_out, DIM, DIM, flag, 1);
    } else {
        // legacy path: dynamic-dtype GEMMs, no extra workspace
        gemm_nt<<<dim3(SEQ / 128, DIM / 128), blk, 0, stream>>>(x, wq, Qb, DIM, DIM, flag, 1, 1, 0);
        gemm_nt<<<dim3(SEQ / 128, KVDIM / 128), blk, 0, stream>>>(x, wk, Kb, DIM, KVDIM, flag, 1, 1, 0);
        gemm_nt<<<dim3(SEQ / 128, KVDIM / 128), blk, 0, stream>>>(x, wv, Vb, DIM, KVDIM, flag, 1, 1, 0);
        rope_k<<<(SEQ * NH * 64) / 256, 256, 0, stream>>>(Qb, NH);
        rope_k<<<(SEQ * NKV * 64) / 256, 256, 0, stream>>>(Kb, NKV);
        attn_k<<<NH * (SEQ / 128), blk, 0, stream>>>(Qb, Kb, Vb, Ab);
        gemm_nt<<<dim3(SEQ / 128, DIM / 128), blk, 0, stream>>>(Ab, wo, d_out, DIM, DIM, flag, 0, 1, 1);
    }
}

// Round 2
// 690.141 us; speedup vs baseline: 1.9154x; 1.0866x over previous
//
#include <hip/hip_runtime.h>
#include <stdint.h>
#include <math.h>

#define DIM 4096
#define NH 32
#define NKV 8
#define HD 128
#define SEQ 2048
#define KVDIM (NKV * HD)   // 1024

typedef __bf16 bf16x8 __attribute__((ext_vector_type(8)));
typedef float floatx4 __attribute__((ext_vector_type(4)));
typedef uint16_t u16x8 __attribute__((ext_vector_type(8)));

#define AS1C(p) ((const __attribute__((address_space(1))) void*)(p))
#define AS3(p)  ((__attribute__((address_space(3))) void*)(p))

__device__ __forceinline__ float b2f(uint16_t u) {
    union { uint32_t i; float f; } v; v.i = ((uint32_t)u) << 16; return v.f;
}
__device__ __forceinline__ uint16_t f2b(float f) {
    union { float f; uint32_t i; } v; v.f = f;
    uint32_t r = v.i + 0x7fffu + ((v.i >> 16) & 1u);   // RTNE
    return (uint16_t)(r >> 16);
}

// Load 8 logical bf16 elements starting at element index e of buffer p,
// where p is bf16 (isf32=false) or f32 (isf32=true; convert to bf16).
__device__ __forceinline__ u16x8 ldchunk(const void* p, bool isf32, size_t e) {
    if (isf32) {
        const float* fp = (const float*)p + e;
        u16x8 r;
#pragma unroll
        for (int j = 0; j < 8; ++j) r[j] = f2b(fp[j]);
        return r;
    }
    return *(const u16x8*)((const uint16_t*)p + e);
}

// ---------------------------------------------------------------------------
// dtype detector: interpret first 4096 elements of x as bf16. True bf16
// N(0,1) data -> 0 "bad"; f32 data misread as bf16 -> ~40% bad.
// flag: 0 = bf16 inputs, 1 = f32 inputs.
// ---------------------------------------------------------------------------
__global__ void detect_k(const uint16_t* __restrict__ x, int* __restrict__ flag) {
    __shared__ int cnt;
    if (threadIdx.x == 0) cnt = 0;
    __syncthreads();
    int bad = 0;
    for (int i = threadIdx.x; i < 4096; i += 256) {
        float v = b2f(x[i]);
        if (!(fabsf(v) < 1e6f)) bad++;   // NaN compares false -> counted
    }
    atomicAdd(&cnt, bad);
    __syncthreads();
    if (threadIdx.x == 0) *flag = (cnt > 256) ? 1 : 0;
}

// ---------------------------------------------------------------------------
// convert kernel: f32 -> bf16 (flag==1) or bf16 copy (flag==0). n % 8 == 0.
// ---------------------------------------------------------------------------
__global__ __launch_bounds__(256) void conv_k(const void* __restrict__ src,
                                              uint16_t* __restrict__ dst,
                                              size_t n,
                                              const int* __restrict__ flagp) {
    const int f = *flagp;
    size_t i = ((size_t)blockIdx.x * blockDim.x + threadIdx.x) * 8;
    const size_t stride = (size_t)gridDim.x * blockDim.x * 8;
    if (f) {
        for (; i < n; i += stride) {
            const float* s = (const float*)src + i;
            u16x8 r;
#pragma unroll
            for (int j = 0; j < 8; ++j) r[j] = f2b(s[j]);
            *(u16x8*)(dst + i) = r;
        }
    } else {
        for (; i < n; i += stride)
            *(u16x8*)(dst + i) = *(const u16x8*)((const uint16_t*)src + i);
    }
}

// ---------------------------------------------------------------------------
// Legacy NT GEMM (fallback when workspace too small): dynamic dtype operands.
// ---------------------------------------------------------------------------
__global__ __launch_bounds__(256) void gemm_nt(const void* __restrict__ A,
                                               const void* __restrict__ B,
                                               void* __restrict__ C,
                                               int K, int ldc,
                                               const int* __restrict__ flagp,
                                               int a_dyn, int b_dyn, int out_dyn) {
    __shared__ uint16_t As[128 * 64];
    __shared__ uint16_t Bs[128 * 64];
    const int f = *flagp;
    const bool af32 = a_dyn && f, bf32 = b_dyn && f, of32 = out_dyn && f;
    const int tid = threadIdx.x;
    const int wave = tid >> 6, lane = tid & 63;
    const int wh = wave >> 1, ww = wave & 1;
    const int quad = lane >> 4, l16 = lane & 15;
    const int m0 = blockIdx.x * 128;
    const int n0 = blockIdx.y * 128;

    floatx4 acc[4][4] = {};

    for (int k0 = 0; k0 < K; k0 += 64) {
        __syncthreads();
#pragma unroll
        for (int it = 0; it < 4; ++it) {
            int id = tid + it * 256;
            int row = id >> 3, slot = id & 7;
            int c8 = ((slot ^ (row & 7)) << 3);
            u16x8 va = ldchunk(A, af32, (size_t)(m0 + row) * K + k0 + c8);
            *(u16x8*)(As + row * 64 + slot * 8) = va;
            u16x8 vb = ldchunk(B, bf32, (size_t)(n0 + row) * K + k0 + c8);
            *(u16x8*)(Bs + row * 64 + slot * 8) = vb;
        }
        __syncthreads();
#pragma unroll
        for (int ks = 0; ks < 2; ++ks) {
            bf16x8 af[4], bf[4];
#pragma unroll
            for (int mi = 0; mi < 4; ++mi) {
                int r = wh * 64 + mi * 16 + l16;
                int slot = (ks * 4 + quad) ^ (r & 7);
                af[mi] = *(const bf16x8*)(As + r * 64 + slot * 8);
            }
#pragma unroll
            for (int ni = 0; ni < 4; ++ni) {
                int r = ww * 64 + ni * 16 + l16;
                int slot = (ks * 4 + quad) ^ (r & 7);
                bf[ni] = *(const bf16x8*)(Bs + r * 64 + slot * 8);
            }
#pragma unroll
            for (int mi = 0; mi < 4; ++mi)
#pragma unroll
                for (int ni = 0; ni < 4; ++ni)
                    acc[mi][ni] = __builtin_amdgcn_mfma_f32_16x16x32_bf16(
                        af[mi], bf[ni], acc[mi][ni], 0, 0, 0);
        }
    }
#pragma unroll
    for (int mi = 0; mi < 4; ++mi) {
#pragma unroll
        for (int ni = 0; ni < 4; ++ni) {
            int row = m0 + wh * 64 + mi * 16 + quad * 4;
            int col = n0 + ww * 64 + ni * 16 + l16;
            if (of32) {
#pragma unroll
                for (int i = 0; i < 4; ++i)
                    ((float*)C)[(size_t)(row + i) * ldc + col] = acc[mi][ni][i];
            } else {
#pragma unroll
                for (int i = 0; i < 4; ++i)
                    ((uint16_t*)C)[(size_t)(row + i) * ldc + col] = f2b(acc[mi][ni][i]);
            }
        }
    }
}

// ---------------------------------------------------------------------------
// Fast NT GEMM: pure bf16 operands, global_load_lds(16B) staging.
// ---------------------------------------------------------------------------
__global__ __launch_bounds__(256) void gemm_bf(const uint16_t* __restrict__ A,
                                               const uint16_t* __restrict__ B,
                                               void* __restrict__ C,
                                               int K, int ldc,
                                               const int* __restrict__ flagp,
                                               int out_dyn) {
    __shared__ uint16_t As[128 * 64];
    __shared__ uint16_t Bs[128 * 64];
    const bool of32 = out_dyn && (*flagp);
    const int tid = threadIdx.x;
    const int wave = tid >> 6, lane = tid & 63;
    const int wh = wave >> 1, ww = wave & 1;
    const int quad = lane >> 4, l16 = lane & 15;
    const int m0 = blockIdx.x * 128;
    const int n0 = blockIdx.y * 128;

    floatx4 acc[4][4] = {};

    for (int k0 = 0; k0 < K; k0 += 64) {
        __syncthreads();   // prior iteration's LDS reads done
#pragma unroll
        for (int it = 0; it < 4; ++it) {
            int id = tid + it * 256;          // chunk id 0..1023
            int row = id >> 3, slot = id & 7;
            int c8 = ((slot ^ (row & 7)) << 3);
            __builtin_amdgcn_global_load_lds(
                AS1C(A + (size_t)(m0 + row) * K + k0 + c8),
                AS3(As + (size_t)(it * 256 + wave * 64) * 8), 16, 0, 0);
            __builtin_amdgcn_global_load_lds(
                AS1C(B + (size_t)(n0 + row) * K + k0 + c8),
                AS3(Bs + (size_t)(it * 256 + wave * 64) * 8), 16, 0, 0);
        }
        __syncthreads();   // vmcnt(0) drain + barrier: tiles visible
#pragma unroll
        for (int ks = 0; ks < 2; ++ks) {
            bf16x8 af[4], bf[4];
#pragma unroll
            for (int mi = 0; mi < 4; ++mi) {
                int r = wh * 64 + mi * 16 + l16;
                int slot = (ks * 4 + quad) ^ (r & 7);
                af[mi] = *(const bf16x8*)(As + r * 64 + slot * 8);
            }
#pragma unroll
            for (int ni = 0; ni < 4; ++ni) {
                int r = ww * 64 + ni * 16 + l16;
                int slot = (ks * 4 + quad) ^ (r & 7);
                bf[ni] = *(const bf16x8*)(Bs + r * 64 + slot * 8);
            }
#pragma unroll
            for (int mi = 0; mi < 4; ++mi)
#pragma unroll
                for (int ni = 0; ni < 4; ++ni)
                    acc[mi][ni] = __builtin_amdgcn_mfma_f32_16x16x32_bf16(
                        af[mi], bf[ni], acc[mi][ni], 0, 0, 0);
        }
    }
    // epilogue: C/D layout row = quad*4 + i, col = lane&15
#pragma unroll
    for (int mi = 0; mi < 4; ++mi) {
#pragma unroll
        for (int ni = 0; ni < 4; ++ni) {
            int row = m0 + wh * 64 + mi * 16 + quad * 4;
            int col = n0 + ww * 64 + ni * 16 + l16;
            if (of32) {
#pragma unroll
                for (int i = 0; i < 4; ++i)
                    ((float*)C)[(size_t)(row + i) * ldc + col] = acc[mi][ni][i];
            } else {
#pragma unroll
                for (int i = 0; i < 4; ++i)
                    ((uint16_t*)C)[(size_t)(row + i) * ldc + col] = f2b(acc[mi][ni][i]);
            }
        }
    }
}

// ---------------------------------------------------------------------------
// RoPE in-place on [SEQ][heads*HD] bf16 buffer (interleaved even/odd pairs)
// ---------------------------------------------------------------------------
__global__ void rope_k(uint16_t* __restrict__ buf, int heads) {
    int id = blockIdx.x * blockDim.x + threadIdx.x;
    int i = id & 63;
    int h = (id >> 6) % heads;
    int t = id / (64 * heads);
    uint16_t* p = buf + (size_t)t * (heads * HD) + h * HD + 2 * i;
    float e = b2f(p[0]), o = b2f(p[1]);
    float freq = exp2f(-(float)(2 * i) * (18.93156857f / 128.0f));
    float ang = (float)t * freq;
    float s, c;
    sincosf(ang, &s, &c);
    p[0] = f2b(e * c - o * s);
    p[1] = f2b(e * s + o * c);
}

// ---------------------------------------------------------------------------
// Flash attention (causal, GQA rep=4). One block = (head, 128-q-row tile).
// 256 threads = 4 waves; wave w owns q-rows [w*32, w*32+32), ALL keys of the
// tile -> softmax is fully wave-local (no cross-wave LDS reduction).
// KV tile = 64 keys. Q fragments hoisted to registers (loaded once).
// LDS 48 KB -> 2 blocks/CU (vs 100 KB / 1 block before).
// Swizzles: Ks 16-slot ^(r&7); Vt 8-slot ^(d&7); Pb 8-slot ^(q&7)^((q>>3)&7)
// (the extra bit kills the quad0/quad2 4-way write conflict).
// ---------------------------------------------------------------------------
__global__ __launch_bounds__(256, 2) void attn_k(const uint16_t* __restrict__ Q,
                                                 const uint16_t* __restrict__ Kg,
                                                 const uint16_t* __restrict__ Vg,
                                                 uint16_t* __restrict__ O) {
    __shared__ uint16_t lds[3 * 64 * 128];   // 48 KB
    uint16_t* Ks = lds;            // [64 keys][128 k]  (16 chunk-slots/row)
    uint16_t* Vt = lds + 8192;     // [128 d][64 keys]  (8 slots/row)
    uint16_t* Pb = lds + 16384;    // [128 q][64 keys]  (8 slots/row)
    uint16_t* Qs = lds;            // prologue alias: [128 q][128 k] (32 KB)

    const int tid = threadIdx.x;
    const int wave = tid >> 6, lane = tid & 63;
    const int quad = lane >> 4, l16 = lane & 15;

    const int qt = 15 - (blockIdx.x >> 5);   // heavy q-tiles first
    const int h = blockIdx.x & 31;
    const int kvh = h >> 2;
    const int q0 = qt * 128;

    // ---- prologue: stage Q tile, hoist per-wave A-fragments to registers --
#pragma unroll
    for (int it = 0; it < 8; ++it) {
        int id = tid + it * 256;
        int row = id >> 4, slot = id & 15;
        int c8 = ((slot ^ (row & 7)) << 3);
        __builtin_amdgcn_global_load_lds(
            AS1C(Q + (size_t)(q0 + row) * DIM + h * HD + c8),
            AS3(Qs + (size_t)(it * 256 + wave * 64) * 8), 16, 0, 0);
    }
    __syncthreads();   // Q visible
    bf16x8 qf[2][4];
#pragma unroll
    for (int mi = 0; mi < 2; ++mi)
#pragma unroll
        for (int ks = 0; ks < 4; ++ks) {
            int r = wave * 32 + mi * 16 + l16;
            int slot = (ks * 4 + quad) ^ (r & 7);
            qf[mi][ks] = *(const bf16x8*)(Qs + r * 128 + slot * 8);
        }

    floatx4 acc_o[2][8] = {};
    float m_run[2][4], l_run[2][4];
#pragma unroll
    for (int mi = 0; mi < 2; ++mi)
#pragma unroll
        for (int i = 0; i < 4; ++i) { m_run[mi][i] = -__builtin_inff(); l_run[mi][i] = 0.f; }

    const float scale = 0.08838834764831845f;  // 1/sqrt(128)
    const float LOG2E = 1.44269504f;

    const int nkt = 2 * qt + 2;
    for (int kt2 = 0; kt2 < nkt; ++kt2) {
        const int k0 = kt2 * 64;
        const bool diag = (kt2 >= 2 * qt);
        __syncthreads();   // A: prior PV reads of Pb/Vt + qf reads done

        // stage K tile (64 x 128) via global_load_lds, swizzled source
#pragma unroll
        for (int it = 0; it < 4; ++it) {
            int id = tid + it * 256;
            int row = id >> 4, slot = id & 15;
            int c8 = ((slot ^ (row & 7)) << 3);
            __builtin_amdgcn_global_load_lds(
                AS1C(Kg + (size_t)(k0 + row) * KVDIM + kvh * HD + c8),
                AS3(Ks + (size_t)(it * 256 + wave * 64) * 8), 16, 0, 0);
        }
        // stage V transposed: Vt[d][key]
        {
            int key = tid & 63;
            int dq = tid >> 6;
#pragma unroll
            for (int it = 0; it < 4; ++it) {
                int dc = dq * 4 + it;
                u16x8 v = *(const u16x8*)(Vg + (size_t)(k0 + key) * KVDIM + kvh * HD + dc * 8);
#pragma unroll
                for (int j = 0; j < 8; ++j) {
                    int d = dc * 8 + j;
                    int slot = ((key >> 3) ^ (d & 7)) & 7;
                    Vt[d * 64 + slot * 8 + (key & 7)] = v[j];
                }
            }
        }
        __syncthreads();   // B: staging visible

        // S = Q K^T  (acc_s[mi][ni]: rows 16, keys 16 per frag)
        floatx4 acc_s[2][4] = {};
        __builtin_amdgcn_s_setprio(1);
#pragma unroll
        for (int ks = 0; ks < 4; ++ks) {
            bf16x8 kf[4];
#pragma unroll
            for (int ni = 0; ni < 4; ++ni) {
                int r = ni * 16 + l16;
                int slot = (ks * 4 + quad) ^ (r & 7);
                kf[ni] = *(const bf16x8*)(Ks + r * 128 + slot * 8);
            }
#pragma unroll
            for (int mi = 0; mi < 2; ++mi)
#pragma unroll
                for (int ni = 0; ni < 4; ++ni)
                    acc_s[mi][ni] = __builtin_amdgcn_mfma_f32_16x16x32_bf16(
                        qf[mi][ks], kf[ni], acc_s[mi][ni], 0, 0, 0);
        }
        __builtin_amdgcn_s_setprio(0);

        // scale + causal mask (only the last two tiles touch the diagonal)
#pragma unroll
        for (int mi = 0; mi < 2; ++mi)
#pragma unroll
            for (int ni = 0; ni < 4; ++ni)
#pragma unroll
                for (int i = 0; i < 4; ++i) {
                    float s = acc_s[mi][ni][i] * scale;
                    if (diag) {
                        int ql = q0 + wave * 32 + mi * 16 + quad * 4 + i;
                        int kl = k0 + ni * 16 + l16;
                        if (kl > ql) s = -__builtin_inff();
                    }
                    acc_s[mi][ni][i] = s;
                }

        // wave-local online softmax; write P (bf16) into Pb
        float alpha[2][4];
#pragma unroll
        for (int mi = 0; mi < 2; ++mi)
#pragma unroll
            for (int i = 0; i < 4; ++i) {
                float v = fmaxf(fmaxf(acc_s[mi][0][i], acc_s[mi][1][i]),
                                fmaxf(acc_s[mi][2][i], acc_s[mi][3][i]));
#pragma unroll
                for (int off = 1; off < 16; off <<= 1)
                    v = fmaxf(v, __shfl_xor(v, off));
                float mn = fmaxf(m_run[mi][i], v);
                alpha[mi][i] = exp2f((m_run[mi][i] - mn) * LOG2E);
                m_run[mi][i] = mn;

                int ql = wave * 32 + mi * 16 + quad * 4 + i;
                float sum = 0.f;
#pragma unroll
                for (int ni = 0; ni < 4; ++ni) {
                    float p = exp2f((acc_s[mi][ni][i] - mn) * LOG2E);
                    sum += p;
                    int key = ni * 16 + l16;
                    int slot = ((key >> 3) ^ (ql & 7) ^ ((ql >> 3) & 7)) & 7;
                    Pb[ql * 64 + slot * 8 + (key & 7)] = f2b(p);
                }
#pragma unroll
                for (int off = 1; off < 16; off <<= 1)
                    sum += __shfl_xor(sum, off);
                l_run[mi][i] = l_run[mi][i] * alpha[mi][i] + sum;
            }

        // rescale O accumulator
#pragma unroll
        for (int mi = 0; mi < 2; ++mi)
#pragma unroll
            for (int ni = 0; ni < 8; ++ni)
#pragma unroll
                for (int i = 0; i < 4; ++i)
                    acc_o[mi][ni][i] *= alpha[mi][i];

        __syncthreads();   // C: P visible (Ks reads all done too)

        // O += P V  (P: A-operand from Pb, V^T: B-operand from Vt)
        __builtin_amdgcn_s_setprio(1);
#pragma unroll
        for (int ks2 = 0; ks2 < 2; ++ks2) {
            bf16x8 pf[2], vf[8];
#pragma unroll
            for (int mi = 0; mi < 2; ++mi) {
                int r = wave * 32 + mi * 16 + l16;
                int slot = ((ks2 * 4 + quad) ^ (r & 7) ^ ((r >> 3) & 7)) & 7;
                pf[mi] = *(const bf16x8*)(Pb + r * 64 + slot * 8);
            }
#pragma unroll
            for (int ni = 0; ni < 8; ++ni) {
                int d = ni * 16 + l16;
                int slot = ((ks2 * 4 + quad) ^ (d & 7)) & 7;
                vf[ni] = *(const bf16x8*)(Vt + d * 64 + slot * 8);
            }
#pragma unroll
            for (int mi = 0; mi < 2; ++mi)
#pragma unroll
                for (int ni = 0; ni < 8; ++ni)
                    acc_o[mi][ni] = __builtin_amdgcn_mfma_f32_16x16x32_bf16(
                        pf[mi], vf[ni], acc_o[mi][ni], 0, 0, 0);
        }
        __builtin_amdgcn_s_setprio(0);
    }

    // epilogue
#pragma unroll
    for (int mi = 0; mi < 2; ++mi)
#pragma unroll
        for (int i = 0; i < 4; ++i) {
            float inv = 1.0f / l_run[mi][i];
            int row = q0 + wave * 32 + mi * 16 + quad * 4 + i;
#pragma unroll
            for (int ni = 0; ni < 8; ++ni) {
                int col = h * HD + ni * 16 + l16;
                O[(size_t)row * DIM + col] = f2b(acc_o[mi][ni][i] * inv);
            }
        }
}

extern "C" void kernel_launch(void* const* d_in, const int* in_sizes, int n_in,
                              void* d_out, int out_size, void* d_ws, size_t ws_size,
                              hipStream_t stream) {
    const void* x  = d_in[0];
    const void* wq = d_in[1];
    const void* wk = d_in[2];
    const void* wv = d_in[3];
    const void* wo = d_in[4];

    // ws layout: [flag 256B][Kb 4.2MB][Vb 4.2MB][Ab 16.8MB]
    // fast path adds: [xb 16.8MB][W1 33.6MB (wq->wo)][W2 8.4MB (wk->wv)]
    int* flag = (int*)d_ws;
    uint16_t* Kb = (uint16_t*)((char*)d_ws + 256);
    uint16_t* Vb = Kb + (size_t)SEQ * KVDIM;
    uint16_t* Ab = Vb + (size_t)SEQ * KVDIM;
    // Q lives in d_out (dead before the final GEMM overwrites d_out)
    uint16_t* Qb = (uint16_t*)d_out;

    const size_t fixed = 256 + 2 * (size_t)SEQ * KVDIM * 2 + (size_t)SEQ * DIM * 2;
    const size_t extra = (size_t)SEQ * DIM * 2      // xb
                       + (size_t)DIM * DIM * 2      // W1
                       + (size_t)KVDIM * DIM * 2;   // W2

    dim3 blk(256);
    detect_k<<<1, blk, 0, stream>>>((const uint16_t*)x, flag);

    if (ws_size >= fixed + extra) {
        // fast path: pre-convert to bf16, global_load_lds GEMMs
        uint16_t* xb = Ab + (size_t)SEQ * DIM;
        uint16_t* W1 = xb + (size_t)SEQ * DIM;
        uint16_t* W2 = W1 + (size_t)DIM * DIM;

        conv_k<<<2048, blk, 0, stream>>>(x, xb, (size_t)SEQ * DIM, flag);
        conv_k<<<2048, blk, 0, stream>>>(wq, W1, (size_t)DIM * DIM, flag);
        gemm_bf<<<dim3(SEQ / 128, DIM / 128), blk, 0, stream>>>(xb, W1, Qb, DIM, DIM, flag, 0);
        conv_k<<<2048, blk, 0, stream>>>(wk, W2, (size_t)KVDIM * DIM, flag);
        gemm_bf<<<dim3(SEQ / 128, KVDIM / 128), blk, 0, stream>>>(xb, W2, Kb, DIM, KVDIM, flag, 0);
        conv_k<<<2048, blk, 0, stream>>>(wv, W2, (size_t)KVDIM * DIM, flag);   // W2 free after wk GEMM (stream order)
        gemm_bf<<<dim3(SEQ / 128, KVDIM / 128), blk, 0, stream>>>(xb, W2, Vb, DIM, KVDIM, flag, 0);
        rope_k<<<(SEQ * NH * 64) / 256, 256, 0, stream>>>(Qb, NH);
        rope_k<<<(SEQ * NKV * 64) / 256, 256, 0, stream>>>(Kb, NKV);
        attn_k<<<NH * (SEQ / 128), blk, 0, stream>>>(Qb, Kb, Vb, Ab);
        conv_k<<<2048, blk, 0, stream>>>(wo, W1, (size_t)DIM * DIM, flag);     // W1 free after wq GEMM
        gemm_bf<<<dim3(SEQ / 128, DIM / 128), blk, 0, stream>>>(Ab, W1, d_out, DIM, DIM, flag, 1);
    } else {
        // legacy path: dynamic-dtype GEMMs, no extra workspace
        gemm_nt<<<dim3(SEQ / 128, DIM / 128), blk, 0, stream>>>(x, wq, Qb, DIM, DIM, flag, 1, 1, 0);
        gemm_nt<<<dim3(SEQ / 128, KVDIM / 128), blk, 0, stream>>>(x, wk, Kb, DIM, KVDIM, flag, 1, 1, 0);
        gemm_nt<<<dim3(SEQ / 128, KVDIM / 128), blk, 0, stream>>>(x, wv, Vb, DIM, KVDIM, flag, 1, 1, 0);
        rope_k<<<(SEQ * NH * 64) / 256, 256, 0, stream>>>(Qb, NH);
        rope_k<<<(SEQ * NKV * 64) / 256, 256, 0, stream>>>(Kb, NKV);
        attn_k<<<NH * (SEQ / 128), blk, 0, stream>>>(Qb, Kb, Vb, Ab);
        gemm_nt<<<dim3(SEQ / 128, DIM / 128), blk, 0, stream>>>(Ab, wo, d_out, DIM, DIM, flag, 0, 1, 1);
    }
}

// Round 3
// 634.085 us; speedup vs baseline: 2.0847x; 1.0884x over previous
//
#include <hip/hip_runtime.h>
#include <stdint.h>
#include <math.h>

#define DIM 4096
#define NH 32
#define NKV 8
#define HD 128
#define SEQ 2048
#define KVDIM (NKV * HD)   // 1024

typedef __bf16 bf16x8 __attribute__((ext_vector_type(8)));
typedef float floatx4 __attribute__((ext_vector_type(4)));
typedef uint16_t u16x8 __attribute__((ext_vector_type(8)));

#define AS1C(p) ((const __attribute__((address_space(1))) void*)(p))
#define AS3(p)  ((__attribute__((address_space(3))) void*)(p))

__device__ __forceinline__ float b2f(uint16_t u) {
    union { uint32_t i; float f; } v; v.i = ((uint32_t)u) << 16; return v.f;
}
__device__ __forceinline__ uint16_t f2b(float f) {
    union { float f; uint32_t i; } v; v.f = f;
    uint32_t r = v.i + 0x7fffu + ((v.i >> 16) & 1u);   // RTNE
    return (uint16_t)(r >> 16);
}

// Load 8 logical bf16 elements starting at element index e of buffer p,
// where p is bf16 (isf32=false) or f32 (isf32=true; convert to bf16).
__device__ __forceinline__ u16x8 ldchunk(const void* p, bool isf32, size_t e) {
    if (isf32) {
        const float* fp = (const float*)p + e;
        u16x8 r;
#pragma unroll
        for (int j = 0; j < 8; ++j) r[j] = f2b(fp[j]);
        return r;
    }
    return *(const u16x8*)((const uint16_t*)p + e);
}

// ---------------------------------------------------------------------------
// dtype detector: flag 0 = bf16 inputs, 1 = f32 inputs.
// ---------------------------------------------------------------------------
__global__ void detect_k(const uint16_t* __restrict__ x, int* __restrict__ flag) {
    __shared__ int cnt;
    if (threadIdx.x == 0) cnt = 0;
    __syncthreads();
    int bad = 0;
    for (int i = threadIdx.x; i < 4096; i += 256) {
        float v = b2f(x[i]);
        if (!(fabsf(v) < 1e6f)) bad++;   // NaN compares false -> counted
    }
    atomicAdd(&cnt, bad);
    __syncthreads();
    if (threadIdx.x == 0) *flag = (cnt > 256) ? 1 : 0;
}

// ---------------------------------------------------------------------------
// convert kernel: f32 -> bf16 (flag==1) or bf16 copy (flag==0). n % 8 == 0.
// ---------------------------------------------------------------------------
__global__ __launch_bounds__(256) void conv_k(const void* __restrict__ src,
                                              uint16_t* __restrict__ dst,
                                              size_t n,
                                              const int* __restrict__ flagp) {
    const int f = *flagp;
    size_t i = ((size_t)blockIdx.x * blockDim.x + threadIdx.x) * 8;
    const size_t stride = (size_t)gridDim.x * blockDim.x * 8;
    if (f) {
        for (; i < n; i += stride) {
            const float* s = (const float*)src + i;
            u16x8 r;
#pragma unroll
            for (int j = 0; j < 8; ++j) r[j] = f2b(s[j]);
            *(u16x8*)(dst + i) = r;
        }
    } else {
        for (; i < n; i += stride)
            *(u16x8*)(dst + i) = *(const u16x8*)((const uint16_t*)src + i);
    }
}

// ---------------------------------------------------------------------------
// Legacy NT GEMM (fallback when workspace too small): dynamic dtype operands.
// out_trans: write C^T (bf16) at CT[col][row], ldc = row stride of CT.
// ---------------------------------------------------------------------------
__global__ __launch_bounds__(256) void gemm_nt(const void* __restrict__ A,
                                               const void* __restrict__ B,
                                               void* __restrict__ C,
                                               int K, int ldc,
                                               const int* __restrict__ flagp,
                                               int a_dyn, int b_dyn, int out_dyn,
                                               int out_trans) {
    __shared__ uint16_t As[128 * 64];
    __shared__ uint16_t Bs[128 * 64];
    const int f = *flagp;
    const bool af32 = a_dyn && f, bf32 = b_dyn && f, of32 = out_dyn && f;
    const int tid = threadIdx.x;
    const int wave = tid >> 6, lane = tid & 63;
    const int wh = wave >> 1, ww = wave & 1;
    const int quad = lane >> 4, l16 = lane & 15;
    const int m0 = blockIdx.x * 128;
    const int n0 = blockIdx.y * 128;

    floatx4 acc[4][4] = {};

    for (int k0 = 0; k0 < K; k0 += 64) {
        __syncthreads();
#pragma unroll
        for (int it = 0; it < 4; ++it) {
            int id = tid + it * 256;
            int row = id >> 3, slot = id & 7;
            int c8 = ((slot ^ (row & 7)) << 3);
            u16x8 va = ldchunk(A, af32, (size_t)(m0 + row) * K + k0 + c8);
            *(u16x8*)(As + row * 64 + slot * 8) = va;
            u16x8 vb = ldchunk(B, bf32, (size_t)(n0 + row) * K + k0 + c8);
            *(u16x8*)(Bs + row * 64 + slot * 8) = vb;
        }
        __syncthreads();
#pragma unroll
        for (int ks = 0; ks < 2; ++ks) {
            bf16x8 af[4], bf[4];
#pragma unroll
            for (int mi = 0; mi < 4; ++mi) {
                int r = wh * 64 + mi * 16 + l16;
                int slot = (ks * 4 + quad) ^ (r & 7);
                af[mi] = *(const bf16x8*)(As + r * 64 + slot * 8);
            }
#pragma unroll
            for (int ni = 0; ni < 4; ++ni) {
                int r = ww * 64 + ni * 16 + l16;
                int slot = (ks * 4 + quad) ^ (r & 7);
                bf[ni] = *(const bf16x8*)(Bs + r * 64 + slot * 8);
            }
#pragma unroll
            for (int mi = 0; mi < 4; ++mi)
#pragma unroll
                for (int ni = 0; ni < 4; ++ni)
                    acc[mi][ni] = __builtin_amdgcn_mfma_f32_16x16x32_bf16(
                        af[mi], bf[ni], acc[mi][ni], 0, 0, 0);
        }
    }
#pragma unroll
    for (int mi = 0; mi < 4; ++mi) {
#pragma unroll
        for (int ni = 0; ni < 4; ++ni) {
            int row = m0 + wh * 64 + mi * 16 + quad * 4;
            int col = n0 + ww * 64 + ni * 16 + l16;
            if (out_trans) {
                uint64_t pack = 0;
#pragma unroll
                for (int i = 0; i < 4; ++i)
                    pack |= (uint64_t)f2b(acc[mi][ni][i]) << (16 * i);
                *(uint64_t*)((uint16_t*)C + (size_t)col * ldc + row) = pack;
            } else if (of32) {
#pragma unroll
                for (int i = 0; i < 4; ++i)
                    ((float*)C)[(size_t)(row + i) * ldc + col] = acc[mi][ni][i];
            } else {
#pragma unroll
                for (int i = 0; i < 4; ++i)
                    ((uint16_t*)C)[(size_t)(row + i) * ldc + col] = f2b(acc[mi][ni][i]);
            }
        }
    }
}

// ---------------------------------------------------------------------------
// Fast NT GEMM: pure bf16 operands, global_load_lds(16B) staging.
// out_mode: 0 = bf16 row-major; 1 = f32-if-flag row-major; 2 = bf16 C^T
// (CT[col][row], ldc = row stride of CT; used to produce V^T for attn).
// ---------------------------------------------------------------------------
__global__ __launch_bounds__(256) void gemm_bf(const uint16_t* __restrict__ A,
                                               const uint16_t* __restrict__ B,
                                               void* __restrict__ C,
                                               int K, int ldc,
                                               const int* __restrict__ flagp,
                                               int out_mode) {
    __shared__ uint16_t As[128 * 64];
    __shared__ uint16_t Bs[128 * 64];
    const bool of32 = (out_mode == 1) && (*flagp);
    const int tid = threadIdx.x;
    const int wave = tid >> 6, lane = tid & 63;
    const int wh = wave >> 1, ww = wave & 1;
    const int quad = lane >> 4, l16 = lane & 15;
    const int m0 = blockIdx.x * 128;
    const int n0 = blockIdx.y * 128;

    floatx4 acc[4][4] = {};

    for (int k0 = 0; k0 < K; k0 += 64) {
        __syncthreads();   // prior iteration's LDS reads done
#pragma unroll
        for (int it = 0; it < 4; ++it) {
            int id = tid + it * 256;          // chunk id 0..1023
            int row = id >> 3, slot = id & 7;
            int c8 = ((slot ^ (row & 7)) << 3);
            __builtin_amdgcn_global_load_lds(
                AS1C(A + (size_t)(m0 + row) * K + k0 + c8),
                AS3(As + (size_t)(it * 256 + wave * 64) * 8), 16, 0, 0);
            __builtin_amdgcn_global_load_lds(
                AS1C(B + (size_t)(n0 + row) * K + k0 + c8),
                AS3(Bs + (size_t)(it * 256 + wave * 64) * 8), 16, 0, 0);
        }
        __syncthreads();   // vmcnt(0) drain + barrier: tiles visible
#pragma unroll
        for (int ks = 0; ks < 2; ++ks) {
            bf16x8 af[4], bf[4];
#pragma unroll
            for (int mi = 0; mi < 4; ++mi) {
                int r = wh * 64 + mi * 16 + l16;
                int slot = (ks * 4 + quad) ^ (r & 7);
                af[mi] = *(const bf16x8*)(As + r * 64 + slot * 8);
            }
#pragma unroll
            for (int ni = 0; ni < 4; ++ni) {
                int r = ww * 64 + ni * 16 + l16;
                int slot = (ks * 4 + quad) ^ (r & 7);
                bf[ni] = *(const bf16x8*)(Bs + r * 64 + slot * 8);
            }
#pragma unroll
            for (int mi = 0; mi < 4; ++mi)
#pragma unroll
                for (int ni = 0; ni < 4; ++ni)
                    acc[mi][ni] = __builtin_amdgcn_mfma_f32_16x16x32_bf16(
                        af[mi], bf[ni], acc[mi][ni], 0, 0, 0);
        }
    }
    // epilogue: C/D layout row = quad*4 + i, col = lane&15
#pragma unroll
    for (int mi = 0; mi < 4; ++mi) {
#pragma unroll
        for (int ni = 0; ni < 4; ++ni) {
            int row = m0 + wh * 64 + mi * 16 + quad * 4;
            int col = n0 + ww * 64 + ni * 16 + l16;
            if (out_mode == 2) {
                uint64_t pack = 0;
#pragma unroll
                for (int i = 0; i < 4; ++i)
                    pack |= (uint64_t)f2b(acc[mi][ni][i]) << (16 * i);
                *(uint64_t*)((uint16_t*)C + (size_t)col * ldc + row) = pack;
            } else if (of32) {
#pragma unroll
                for (int i = 0; i < 4; ++i)
                    ((float*)C)[(size_t)(row + i) * ldc + col] = acc[mi][ni][i];
            } else {
#pragma unroll
                for (int i = 0; i < 4; ++i)
                    ((uint16_t*)C)[(size_t)(row + i) * ldc + col] = f2b(acc[mi][ni][i]);
            }
        }
    }
}

// ---------------------------------------------------------------------------
// RoPE in-place on [SEQ][heads*HD] bf16 buffer (interleaved even/odd pairs)
// ---------------------------------------------------------------------------
__global__ void rope_k(uint16_t* __restrict__ buf, int heads) {
    int id = blockIdx.x * blockDim.x + threadIdx.x;
    int i = id & 63;
    int h = (id >> 6) % heads;
    int t = id / (64 * heads);
    uint16_t* p = buf + (size_t)t * (heads * HD) + h * HD + 2 * i;
    float e = b2f(p[0]), o = b2f(p[1]);
    float freq = exp2f(-(float)(2 * i) * (18.93156857f / 128.0f));
    float ang = (float)t * freq;
    float s, c;
    sincosf(ang, &s, &c);
    p[0] = f2b(e * c - o * s);
    p[1] = f2b(e * s + o * c);
}

// ---------------------------------------------------------------------------
// Flash attention (causal, GQA rep=4). 512 threads = 8 waves; wave w owns
// q-rows [w*16, w*16+16), ALL keys -> softmax fully wave-local, P buffer
// rows are wave-exclusive (no cross-wave barrier between QK^T and PV).
// Each block processes TWO q-tiles (qt, 15-qt): uniform 36 tile-units/block,
// grid = 256 blocks = 1/CU, 2 waves/SIMD, zero tail.
// K/V double-buffered in LDS; next tile's global_load_lds issued at tile
// start, drained at the single end-of-tile __syncthreads (latency hidden).
// V comes pre-transposed from the V-GEMM (VgT[1024][SEQ]) -> staged with
// global_load_lds + pre-swizzled source (no scalar scatter).
// LDS: Ks 2x16K + Vt 2x16K + Pb 16K + Qs 32K = 112 KB.
// ---------------------------------------------------------------------------
__global__ __launch_bounds__(512, 1) void attn_k(const uint16_t* __restrict__ Q,
                                                 const uint16_t* __restrict__ Kg,
                                                 const uint16_t* __restrict__ VgT,
                                                 uint16_t* __restrict__ O) {
    __shared__ uint16_t Ks[2][64 * 128];
    __shared__ uint16_t Vt[2][128 * 64];
    __shared__ uint16_t Pb[128 * 64];
    __shared__ uint16_t Qs[128 * 128];

    const int tid = threadIdx.x;
    const int wave = tid >> 6, lane = tid & 63;
    const int quad = lane >> 4, l16 = lane & 15;

    const int head = blockIdx.x & 31;
    const int pairid = blockIdx.x >> 5;      // 0..7
    const int kvh = head >> 2;
    const uint16_t* Vh = VgT + (size_t)kvh * HD * SEQ;   // V^T rows for this kv-head

    const float scale = 0.08838834764831845f;  // 1/sqrt(128)
    const float LOG2E = 1.44269504f;

    auto stage_kv = [&](int buf, int k0s) {
#pragma unroll
        for (int it = 0; it < 2; ++it) {
            int id = tid + it * 512;
            int row = id >> 4, slot = id & 15;
            int c8 = ((slot ^ (row & 7)) << 3);
            __builtin_amdgcn_global_load_lds(
                AS1C(Kg + (size_t)(k0s + row) * KVDIM + kvh * HD + c8),
                AS3(Ks[buf] + (size_t)(it * 512 + wave * 64) * 8), 16, 0, 0);
        }
#pragma unroll
        for (int it = 0; it < 2; ++it) {
            int id = tid + it * 512;
            int d = id >> 3, slot = id & 7;
            int c8 = ((slot ^ (d & 7)) << 3);
            __builtin_amdgcn_global_load_lds(
                AS1C(Vh + (size_t)d * SEQ + k0s + c8),
                AS3(Vt[buf] + (size_t)(it * 512 + wave * 64) * 8), 16, 0, 0);
        }
    };

    int g = 0;   // global tile counter (LDS buffer parity)
    for (int half = 0; half < 2; ++half) {
        const int qt = half ? (15 - pairid) : pairid;
        const int q0 = qt * 128;
        const int nkt = 2 * qt + 2;

        // ---- q-tile prologue: stage Q, (first half: also stage tile 0) ----
#pragma unroll
        for (int it = 0; it < 4; ++it) {
            int id = tid + it * 512;
            int row = id >> 4, slot = id & 15;
            int c8 = ((slot ^ (row & 7)) << 3);
            __builtin_amdgcn_global_load_lds(
                AS1C(Q + (size_t)(q0 + row) * DIM + head * HD + c8),
                AS3(Qs + (size_t)(it * 512 + wave * 64) * 8), 16, 0, 0);
        }
        if (half == 0) stage_kv(0, 0);
        __syncthreads();   // Q (and prefetched tile) visible

        bf16x8 qf[4];
#pragma unroll
        for (int ks = 0; ks < 4; ++ks) {
            int r = wave * 16 + l16;
            int slot = (ks * 4 + quad) ^ (r & 7);
            qf[ks] = *(const bf16x8*)(Qs + r * 128 + slot * 8);
        }

        floatx4 acc_o[8] = {};
        float m_run[4], l_run[4];
#pragma unroll
        for (int i = 0; i < 4; ++i) { m_run[i] = -__builtin_inff(); l_run[i] = 0.f; }

        for (int t = 0; t < nkt; ++t, ++g) {
            const int k0 = t * 64;
            const bool diag = (t >= 2 * qt);
            const int cur = g & 1;

            // prefetch next tile (possibly the other half's tile 0)
            if (!(half == 1 && t == nkt - 1)) {
                int k0n = (t + 1 < nkt) ? (t + 1) * 64 : 0;
                stage_kv((g + 1) & 1, k0n);
            }
            __builtin_amdgcn_sched_barrier(0);   // pin prefetch issue early

            // S = Q K^T
            floatx4 acc_s[4] = {};
            __builtin_amdgcn_s_setprio(1);
#pragma unroll
            for (int ks = 0; ks < 4; ++ks) {
                bf16x8 kf[4];
#pragma unroll
                for (int ni = 0; ni < 4; ++ni) {
                    int r = ni * 16 + l16;
                    int slot = (ks * 4 + quad) ^ (r & 7);
                    kf[ni] = *(const bf16x8*)(Ks[cur] + r * 128 + slot * 8);
                }
#pragma unroll
                for (int ni = 0; ni < 4; ++ni)
                    acc_s[ni] = __builtin_amdgcn_mfma_f32_16x16x32_bf16(
                        qf[ks], kf[ni], acc_s[ni], 0, 0, 0);
            }
            __builtin_amdgcn_s_setprio(0);

            // scale + causal mask
#pragma unroll
            for (int ni = 0; ni < 4; ++ni)
#pragma unroll
                for (int i = 0; i < 4; ++i) {
                    float s = acc_s[ni][i] * scale;
                    if (diag) {
                        int ql = q0 + wave * 16 + quad * 4 + i;
                        int kl = k0 + ni * 16 + l16;
                        if (kl > ql) s = -__builtin_inff();
                    }
                    acc_s[ni][i] = s;
                }

            // wave-local online softmax; write P (bf16) into wave-owned rows
            float alpha[4];
#pragma unroll
            for (int i = 0; i < 4; ++i) {
                float v = fmaxf(fmaxf(acc_s[0][i], acc_s[1][i]),
                                fmaxf(acc_s[2][i], acc_s[3][i]));
#pragma unroll
                for (int off = 1; off < 16; off <<= 1)
                    v = fmaxf(v, __shfl_xor(v, off));
                float mn = fmaxf(m_run[i], v);
                alpha[i] = exp2f((m_run[i] - mn) * LOG2E);
                m_run[i] = mn;

                int ql = wave * 16 + quad * 4 + i;
                float sum = 0.f;
#pragma unroll
                for (int ni = 0; ni < 4; ++ni) {
                    float p = exp2f((acc_s[ni][i] - mn) * LOG2E);
                    sum += p;
                    int key = ni * 16 + l16;
                    int slot = ((key >> 3) ^ (ql & 7) ^ ((ql >> 3) & 7)) & 7;
                    Pb[ql * 64 + slot * 8 + (key & 7)] = f2b(p);
                }
#pragma unroll
                for (int off = 1; off < 16; off <<= 1)
                    sum += __shfl_xor(sum, off);
                l_run[i] = l_run[i] * alpha[i] + sum;
            }

            // rescale O accumulator
#pragma unroll
            for (int ni = 0; ni < 8; ++ni)
#pragma unroll
                for (int i = 0; i < 4; ++i)
                    acc_o[ni][i] *= alpha[i];

            // O += P V  (P rows wave-exclusive: same-wave DS order suffices)
            __builtin_amdgcn_s_setprio(1);
#pragma unroll
            for (int ks2 = 0; ks2 < 2; ++ks2) {
                bf16x8 pf, vf[8];
                {
                    int r = wave * 16 + l16;
                    int slot = ((ks2 * 4 + quad) ^ (r & 7) ^ ((r >> 3) & 7)) & 7;
                    pf = *(const bf16x8*)(Pb + r * 64 + slot * 8);
                }
#pragma unroll
                for (int ni = 0; ni < 8; ++ni) {
                    int d = ni * 16 + l16;
                    int slot = ((ks2 * 4 + quad) ^ (d & 7)) & 7;
                    vf[ni] = *(const bf16x8*)(Vt[cur] + d * 64 + slot * 8);
                }
#pragma unroll
                for (int ni = 0; ni < 8; ++ni)
                    acc_o[ni] = __builtin_amdgcn_mfma_f32_16x16x32_bf16(
                        pf, vf[ni], acc_o[ni], 0, 0, 0);
            }
            __builtin_amdgcn_s_setprio(0);

            __syncthreads();   // drains prefetch (vmcnt) + all LDS; next tile ready
        }

        // ---- epilogue for this q-tile ----
#pragma unroll
        for (int i = 0; i < 4; ++i) {
            float inv = 1.0f / l_run[i];
            int row = q0 + wave * 16 + quad * 4 + i;
#pragma unroll
            for (int ni = 0; ni < 8; ++ni) {
                int col = head * HD + ni * 16 + l16;
                O[(size_t)row * DIM + col] = f2b(acc_o[ni][i] * inv);
            }
        }
    }
}

extern "C" void kernel_launch(void* const* d_in, const int* in_sizes, int n_in,
                              void* d_out, int out_size, void* d_ws, size_t ws_size,
                              hipStream_t stream) {
    const void* x  = d_in[0];
    const void* wq = d_in[1];
    const void* wk = d_in[2];
    const void* wv = d_in[3];
    const void* wo = d_in[4];

    // ws layout: [flag 256B][Kb 4.2MB][VbT 4.2MB][Ab 16.8MB]
    // fast path adds: [xb 16.8MB][W1 33.6MB (wq->wo)][W2 8.4MB (wk->wv)]
    int* flag = (int*)d_ws;
    uint16_t* Kb  = (uint16_t*)((char*)d_ws + 256);
    uint16_t* VbT = Kb + (size_t)SEQ * KVDIM;       // V^T: [KVDIM][SEQ]
    uint16_t* Ab  = VbT + (size_t)SEQ * KVDIM;
    // Q lives in d_out (dead before the final GEMM overwrites d_out)
    uint16_t* Qb = (uint16_t*)d_out;

    const size_t fixed = 256 + 2 * (size_t)SEQ * KVDIM * 2 + (size_t)SEQ * DIM * 2;
    const size_t extra = (size_t)SEQ * DIM * 2      // xb
                       + (size_t)DIM * DIM * 2      // W1
                       + (size_t)KVDIM * DIM * 2;   // W2

    dim3 blk(256);
    detect_k<<<1, blk, 0, stream>>>((const uint16_t*)x, flag);

    if (ws_size >= fixed + extra) {
        // fast path: pre-convert to bf16, global_load_lds GEMMs
        uint16_t* xb = Ab + (size_t)SEQ * DIM;
        uint16_t* W1 = xb + (size_t)SEQ * DIM;
        uint16_t* W2 = W1 + (size_t)DIM * DIM;

        conv_k<<<2048, blk, 0, stream>>>(x, xb, (size_t)SEQ * DIM, flag);
        conv_k<<<2048, blk, 0, stream>>>(wq, W1, (size_t)DIM * DIM, flag);
        gemm_bf<<<dim3(SEQ / 128, DIM / 128), blk, 0, stream>>>(xb, W1, Qb, DIM, DIM, flag, 0);
        conv_k<<<2048, blk, 0, stream>>>(wk, W2, (size_t)KVDIM * DIM, flag);
        gemm_bf<<<dim3(SEQ / 128, KVDIM / 128), blk, 0, stream>>>(xb, W2, Kb, DIM, KVDIM, flag, 0);
        conv_k<<<2048, blk, 0, stream>>>(wv, W2, (size_t)KVDIM * DIM, flag);   // W2 free after wk GEMM
        gemm_bf<<<dim3(SEQ / 128, KVDIM / 128), blk, 0, stream>>>(xb, W2, VbT, DIM, SEQ, flag, 2);
        rope_k<<<(SEQ * NH * 64) / 256, 256, 0, stream>>>(Qb, NH);
        rope_k<<<(SEQ * NKV * 64) / 256, 256, 0, stream>>>(Kb, NKV);
        attn_k<<<NH * 8, dim3(512), 0, stream>>>(Qb, Kb, VbT, Ab);
        conv_k<<<2048, blk, 0, stream>>>(wo, W1, (size_t)DIM * DIM, flag);     // W1 free after wq GEMM
        gemm_bf<<<dim3(SEQ / 128, DIM / 128), blk, 0, stream>>>(Ab, W1, d_out, DIM, DIM, flag, 1);
    } else {
        // legacy path: dynamic-dtype GEMMs, no extra workspace
        gemm_nt<<<dim3(SEQ / 128, DIM / 128), blk, 0, stream>>>(x, wq, Qb, DIM, DIM, flag, 1, 1, 0, 0);
        gemm_nt<<<dim3(SEQ / 128, KVDIM / 128), blk, 0, stream>>>(x, wk, Kb, DIM, KVDIM, flag, 1, 1, 0, 0);
        gemm_nt<<<dim3(SEQ / 128, KVDIM / 128), blk, 0, stream>>>(x, wv, VbT, DIM, SEQ, flag, 1, 1, 0, 1);
        rope_k<<<(SEQ * NH * 64) / 256, 256, 0, stream>>>(Qb, NH);
        rope_k<<<(SEQ * NKV * 64) / 256, 256, 0, stream>>>(Kb, NKV);
        attn_k<<<NH * 8, dim3(512), 0, stream>>>(Qb, Kb, VbT, Ab);
        gemm_nt<<<dim3(SEQ / 128, DIM / 128), blk, 0, stream>>>(Ab, wo, d_out, DIM, DIM, flag, 0, 1, 1, 0);
    }
}

// Round 4
// 515.991 us; speedup vs baseline: 2.5618x; 1.2289x over previous
//
#include <hip/hip_runtime.h>
#include <stdint.h>
#include <math.h>

#define DIM 4096
#define NH 32
#define NKV 8
#define HD 128
#define SEQ 2048
#define KVDIM (NKV * HD)   // 1024
#define QKVDIM (DIM + 2 * KVDIM)   // 6144

typedef __bf16 bf16x8 __attribute__((ext_vector_type(8)));
typedef float floatx4 __attribute__((ext_vector_type(4)));
typedef uint16_t u16x8 __attribute__((ext_vector_type(8)));

#define AS1C(p) ((const __attribute__((address_space(1))) void*)(p))
#define AS3(p)  ((__attribute__((address_space(3))) void*)(p))

__device__ __forceinline__ float b2f(uint16_t u) {
    union { uint32_t i; float f; } v; v.i = ((uint32_t)u) << 16; return v.f;
}
__device__ __forceinline__ uint16_t f2b(float f) {
    union { float f; uint32_t i; } v; v.f = f;
    uint32_t r = v.i + 0x7fffu + ((v.i >> 16) & 1u);   // RTNE
    return (uint16_t)(r >> 16);
}

// Load 8 logical bf16 elements starting at element index e of buffer p,
// where p is bf16 (isf32=false) or f32 (isf32=true; convert to bf16).
__device__ __forceinline__ u16x8 ldchunk(const void* p, bool isf32, size_t e) {
    if (isf32) {
        const float* fp = (const float*)p + e;
        u16x8 r;
#pragma unroll
        for (int j = 0; j < 8; ++j) r[j] = f2b(fp[j]);
        return r;
    }
    return *(const u16x8*)((const uint16_t*)p + e);
}

// ---------------------------------------------------------------------------
// dtype detector: flag 0 = bf16 inputs, 1 = f32 inputs.
// ---------------------------------------------------------------------------
__global__ void detect_k(const uint16_t* __restrict__ x, int* __restrict__ flag) {
    __shared__ int cnt;
    if (threadIdx.x == 0) cnt = 0;
    __syncthreads();
    int bad = 0;
    for (int i = threadIdx.x; i < 4096; i += 256) {
        float v = b2f(x[i]);
        if (!(fabsf(v) < 1e6f)) bad++;   // NaN compares false -> counted
    }
    atomicAdd(&cnt, bad);
    __syncthreads();
    if (threadIdx.x == 0) *flag = (cnt > 256) ? 1 : 0;
}

// ---------------------------------------------------------------------------
// convert kernel: f32 -> bf16 (flag==1) or bf16 copy (flag==0). n % 8 == 0.
// ---------------------------------------------------------------------------
__global__ __launch_bounds__(256) void conv_k(const void* __restrict__ src,
                                              uint16_t* __restrict__ dst,
                                              size_t n,
                                              const int* __restrict__ flagp) {
    const int f = *flagp;
    size_t i = ((size_t)blockIdx.x * blockDim.x + threadIdx.x) * 8;
    const size_t stride = (size_t)gridDim.x * blockDim.x * 8;
    if (f) {
        for (; i < n; i += stride) {
            const float* s = (const float*)src + i;
            u16x8 r;
#pragma unroll
            for (int j = 0; j < 8; ++j) r[j] = f2b(s[j]);
            *(u16x8*)(dst + i) = r;
        }
    } else {
        for (; i < n; i += stride)
            *(u16x8*)(dst + i) = *(const u16x8*)((const uint16_t*)src + i);
    }
}

// ---------------------------------------------------------------------------
// Legacy NT GEMM (fallback when workspace too small): dynamic dtype operands.
// out_trans: write C^T (bf16) at CT[col][row], ldc = row stride of CT.
// ---------------------------------------------------------------------------
__global__ __launch_bounds__(256) void gemm_nt(const void* __restrict__ A,
                                               const void* __restrict__ B,
                                               void* __restrict__ C,
                                               int K, int ldc,
                                               const int* __restrict__ flagp,
                                               int a_dyn, int b_dyn, int out_dyn,
                                               int out_trans) {
    __shared__ uint16_t As[128 * 64];
    __shared__ uint16_t Bs[128 * 64];
    const int f = *flagp;
    const bool af32 = a_dyn && f, bf32 = b_dyn && f, of32 = out_dyn && f;
    const int tid = threadIdx.x;
    const int wave = tid >> 6, lane = tid & 63;
    const int wh = wave >> 1, ww = wave & 1;
    const int quad = lane >> 4, l16 = lane & 15;
    const int m0 = blockIdx.x * 128;
    const int n0 = blockIdx.y * 128;

    floatx4 acc[4][4] = {};

    for (int k0 = 0; k0 < K; k0 += 64) {
        __syncthreads();
#pragma unroll
        for (int it = 0; it < 4; ++it) {
            int id = tid + it * 256;
            int row = id >> 3, slot = id & 7;
            int c8 = ((slot ^ (row & 7)) << 3);
            u16x8 va = ldchunk(A, af32, (size_t)(m0 + row) * K + k0 + c8);
            *(u16x8*)(As + row * 64 + slot * 8) = va;
            u16x8 vb = ldchunk(B, bf32, (size_t)(n0 + row) * K + k0 + c8);
            *(u16x8*)(Bs + row * 64 + slot * 8) = vb;
        }
        __syncthreads();
#pragma unroll
        for (int ks = 0; ks < 2; ++ks) {
            bf16x8 af[4], bf[4];
#pragma unroll
            for (int mi = 0; mi < 4; ++mi) {
                int r = wh * 64 + mi * 16 + l16;
                int slot = (ks * 4 + quad) ^ (r & 7);
                af[mi] = *(const bf16x8*)(As + r * 64 + slot * 8);
            }
#pragma unroll
            for (int ni = 0; ni < 4; ++ni) {
                int r = ww * 64 + ni * 16 + l16;
                int slot = (ks * 4 + quad) ^ (r & 7);
                bf[ni] = *(const bf16x8*)(Bs + r * 64 + slot * 8);
            }
#pragma unroll
            for (int mi = 0; mi < 4; ++mi)
#pragma unroll
                for (int ni = 0; ni < 4; ++ni)
                    acc[mi][ni] = __builtin_amdgcn_mfma_f32_16x16x32_bf16(
                        af[mi], bf[ni], acc[mi][ni], 0, 0, 0);
        }
    }
#pragma unroll
    for (int mi = 0; mi < 4; ++mi) {
#pragma unroll
        for (int ni = 0; ni < 4; ++ni) {
            int row = m0 + wh * 64 + mi * 16 + quad * 4;
            int col = n0 + ww * 64 + ni * 16 + l16;
            if (out_trans) {
                uint64_t pack = 0;
#pragma unroll
                for (int i = 0; i < 4; ++i)
                    pack |= (uint64_t)f2b(acc[mi][ni][i]) << (16 * i);
                *(uint64_t*)((uint16_t*)C + (size_t)col * ldc + row) = pack;
            } else if (of32) {
#pragma unroll
                for (int i = 0; i < 4; ++i)
                    ((float*)C)[(size_t)(row + i) * ldc + col] = acc[mi][ni][i];
            } else {
#pragma unroll
                for (int i = 0; i < 4; ++i)
                    ((uint16_t*)C)[(size_t)(row + i) * ldc + col] = f2b(acc[mi][ni][i]);
            }
        }
    }
}

// ---------------------------------------------------------------------------
// Fast NT GEMM: pure bf16 operands, global_load_lds(16B) staging.
// XCD-chunked bijective blockIdx swizzle when nwg%8==0 (M fastest within
// chunk -> B panel stays hot in that XCD's L2).
// out_mode: 0 = bf16 row-major; 1 = f32-if-flag row-major.
// ---------------------------------------------------------------------------
__global__ __launch_bounds__(256) void gemm_bf(const uint16_t* __restrict__ A,
                                               const uint16_t* __restrict__ B,
                                               void* __restrict__ C,
                                               int K, int ldc,
                                               const int* __restrict__ flagp,
                                               int out_mode) {
    __shared__ uint16_t As[128 * 64];
    __shared__ uint16_t Bs[128 * 64];
    const bool of32 = (out_mode == 1) && (*flagp);
    const int tid = threadIdx.x;
    const int wave = tid >> 6, lane = tid & 63;
    const int wh = wave >> 1, ww = wave & 1;
    const int quad = lane >> 4, l16 = lane & 15;

    int nwg = gridDim.x * gridDim.y;
    int id = blockIdx.y * gridDim.x + blockIdx.x;
    if ((nwg & 7) == 0) {
        int cpx = nwg >> 3;
        id = (id & 7) * cpx + (id >> 3);
    }
    const int m0 = (id % gridDim.x) * 128;
    const int n0 = (id / gridDim.x) * 128;

    floatx4 acc[4][4] = {};

    for (int k0 = 0; k0 < K; k0 += 64) {
        __syncthreads();   // prior iteration's LDS reads done
#pragma unroll
        for (int it = 0; it < 4; ++it) {
            int idc = tid + it * 256;          // chunk id 0..1023
            int row = idc >> 3, slot = idc & 7;
            int c8 = ((slot ^ (row & 7)) << 3);
            __builtin_amdgcn_global_load_lds(
                AS1C(A + (size_t)(m0 + row) * K + k0 + c8),
                AS3(As + (size_t)(it * 256 + wave * 64) * 8), 16, 0, 0);
            __builtin_amdgcn_global_load_lds(
                AS1C(B + (size_t)(n0 + row) * K + k0 + c8),
                AS3(Bs + (size_t)(it * 256 + wave * 64) * 8), 16, 0, 0);
        }
        __syncthreads();   // vmcnt(0) drain + barrier: tiles visible
#pragma unroll
        for (int ks = 0; ks < 2; ++ks) {
            bf16x8 af[4], bf[4];
#pragma unroll
            for (int mi = 0; mi < 4; ++mi) {
                int r = wh * 64 + mi * 16 + l16;
                int slot = (ks * 4 + quad) ^ (r & 7);
                af[mi] = *(const bf16x8*)(As + r * 64 + slot * 8);
            }
#pragma unroll
            for (int ni = 0; ni < 4; ++ni) {
                int r = ww * 64 + ni * 16 + l16;
                int slot = (ks * 4 + quad) ^ (r & 7);
                bf[ni] = *(const bf16x8*)(Bs + r * 64 + slot * 8);
            }
#pragma unroll
            for (int mi = 0; mi < 4; ++mi)
#pragma unroll
                for (int ni = 0; ni < 4; ++ni)
                    acc[mi][ni] = __builtin_amdgcn_mfma_f32_16x16x32_bf16(
                        af[mi], bf[ni], acc[mi][ni], 0, 0, 0);
        }
    }
    // epilogue: C/D layout row = quad*4 + i, col = lane&15
#pragma unroll
    for (int mi = 0; mi < 4; ++mi) {
#pragma unroll
        for (int ni = 0; ni < 4; ++ni) {
            int row = m0 + wh * 64 + mi * 16 + quad * 4;
            int col = n0 + ww * 64 + ni * 16 + l16;
            if (of32) {
#pragma unroll
                for (int i = 0; i < 4; ++i)
                    ((float*)C)[(size_t)(row + i) * ldc + col] = acc[mi][ni][i];
            } else {
#pragma unroll
                for (int i = 0; i < 4; ++i)
                    ((uint16_t*)C)[(size_t)(row + i) * ldc + col] = f2b(acc[mi][ni][i]);
            }
        }
    }
}

// ---------------------------------------------------------------------------
// Fused QKV projection GEMM: A = xb [SEQ][DIM], W = [QKVDIM][DIM] (rows
// 0..4095 wq, 4096..5119 wk, 5120..6143 wv). Epilogue routes by n0:
// Q -> Qo row-major [SEQ][DIM]; K -> Ko row-major [SEQ][KVDIM];
// V -> VoT transposed [KVDIM][SEQ] (attn consumes V^T).
// grid 16x48 = 768 blocks (3/CU), XCD-chunked swizzle.
// ---------------------------------------------------------------------------
__global__ __launch_bounds__(256) void gemm_qkv(const uint16_t* __restrict__ A,
                                                const uint16_t* __restrict__ W,
                                                uint16_t* __restrict__ Qo,
                                                uint16_t* __restrict__ Ko,
                                                uint16_t* __restrict__ VoT) {
    __shared__ uint16_t As[128 * 64];
    __shared__ uint16_t Bs[128 * 64];
    const int tid = threadIdx.x;
    const int wave = tid >> 6, lane = tid & 63;
    const int wh = wave >> 1, ww = wave & 1;
    const int quad = lane >> 4, l16 = lane & 15;

    int nwg = gridDim.x * gridDim.y;           // 768
    int id = blockIdx.y * gridDim.x + blockIdx.x;
    int cpx = nwg >> 3;
    id = (id & 7) * cpx + (id >> 3);           // XCD-chunked, M fastest
    const int m0 = (id % gridDim.x) * 128;
    const int n0 = (id / gridDim.x) * 128;
    const int K = DIM;

    floatx4 acc[4][4] = {};

    for (int k0 = 0; k0 < K; k0 += 64) {
        __syncthreads();
#pragma unroll
        for (int it = 0; it < 4; ++it) {
            int idc = tid + it * 256;
            int row = idc >> 3, slot = idc & 7;
            int c8 = ((slot ^ (row & 7)) << 3);
            __builtin_amdgcn_global_load_lds(
                AS1C(A + (size_t)(m0 + row) * K + k0 + c8),
                AS3(As + (size_t)(it * 256 + wave * 64) * 8), 16, 0, 0);
            __builtin_amdgcn_global_load_lds(
                AS1C(W + (size_t)(n0 + row) * K + k0 + c8),
                AS3(Bs + (size_t)(it * 256 + wave * 64) * 8), 16, 0, 0);
        }
        __syncthreads();
#pragma unroll
        for (int ks = 0; ks < 2; ++ks) {
            bf16x8 af[4], bf[4];
#pragma unroll
            for (int mi = 0; mi < 4; ++mi) {
                int r = wh * 64 + mi * 16 + l16;
                int slot = (ks * 4 + quad) ^ (r & 7);
                af[mi] = *(const bf16x8*)(As + r * 64 + slot * 8);
            }
#pragma unroll
            for (int ni = 0; ni < 4; ++ni) {
                int r = ww * 64 + ni * 16 + l16;
                int slot = (ks * 4 + quad) ^ (r & 7);
                bf[ni] = *(const bf16x8*)(Bs + r * 64 + slot * 8);
            }
#pragma unroll
            for (int mi = 0; mi < 4; ++mi)
#pragma unroll
                for (int ni = 0; ni < 4; ++ni)
                    acc[mi][ni] = __builtin_amdgcn_mfma_f32_16x16x32_bf16(
                        af[mi], bf[ni], acc[mi][ni], 0, 0, 0);
        }
    }
    // epilogue: slice-routed (n0 uniform per block; slices 128-aligned)
#pragma unroll
    for (int mi = 0; mi < 4; ++mi) {
#pragma unroll
        for (int ni = 0; ni < 4; ++ni) {
            int row = m0 + wh * 64 + mi * 16 + quad * 4;
            int col = n0 + ww * 64 + ni * 16 + l16;
            if (n0 < DIM) {
#pragma unroll
                for (int i = 0; i < 4; ++i)
                    Qo[(size_t)(row + i) * DIM + col] = f2b(acc[mi][ni][i]);
            } else if (n0 < DIM + KVDIM) {
                int c = col - DIM;
#pragma unroll
                for (int i = 0; i < 4; ++i)
                    Ko[(size_t)(row + i) * KVDIM + c] = f2b(acc[mi][ni][i]);
            } else {
                int c = col - DIM - KVDIM;
                uint64_t pack = 0;
#pragma unroll
                for (int i = 0; i < 4; ++i)
                    pack |= (uint64_t)f2b(acc[mi][ni][i]) << (16 * i);
                *(uint64_t*)(VoT + (size_t)c * SEQ + row) = pack;
            }
        }
    }
}

// ---------------------------------------------------------------------------
// RoPE in-place on [SEQ][heads*HD] bf16 buffer (interleaved even/odd pairs)
// ---------------------------------------------------------------------------
__global__ void rope_k(uint16_t* __restrict__ buf, int heads) {
    int id = blockIdx.x * blockDim.x + threadIdx.x;
    int i = id & 63;
    int h = (id >> 6) % heads;
    int t = id / (64 * heads);
    uint16_t* p = buf + (size_t)t * (heads * HD) + h * HD + 2 * i;
    float e = b2f(p[0]), o = b2f(p[1]);
    float freq = exp2f(-(float)(2 * i) * (18.93156857f / 128.0f));
    float ang = (float)t * freq;
    float s, c;
    sincosf(ang, &s, &c);
    p[0] = f2b(e * c - o * s);
    p[1] = f2b(e * s + o * c);
}

// ---------------------------------------------------------------------------
// Flash attention (causal, GQA rep=4). 512 threads = 8 waves; wave w owns
// q-rows [w*16, w*16+16), ALL keys -> softmax fully wave-local, P buffer
// rows are wave-exclusive (no cross-wave barrier between QK^T and PV).
// Each block processes TWO q-tiles (qt, 15-qt): uniform 36 tile-units/block,
// grid = 256 blocks = 1/CU, 2 waves/SIMD, zero tail.
// K/V double-buffered in LDS; next tile's global_load_lds issued at tile
// start, drained at the single end-of-tile __syncthreads (latency hidden).
// V comes pre-transposed (VgT[1024][SEQ]) from the QKV GEMM.
// LDS: Ks 2x16K + Vt 2x16K + Pb 16K + Qs 32K = 112 KB.
// ---------------------------------------------------------------------------
__global__ __launch_bounds__(512, 1) void attn_k(const uint16_t* __restrict__ Q,
                                                 const uint16_t* __restrict__ Kg,
                                                 const uint16_t* __restrict__ VgT,
                                                 uint16_t* __restrict__ O) {
    __shared__ uint16_t Ks[2][64 * 128];
    __shared__ uint16_t Vt[2][128 * 64];
    __shared__ uint16_t Pb[128 * 64];
    __shared__ uint16_t Qs[128 * 128];

    const int tid = threadIdx.x;
    const int wave = tid >> 6, lane = tid & 63;
    const int quad = lane >> 4, l16 = lane & 15;

    const int head = blockIdx.x & 31;
    const int pairid = blockIdx.x >> 5;      // 0..7
    const int kvh = head >> 2;
    const uint16_t* Vh = VgT + (size_t)kvh * HD * SEQ;   // V^T rows for this kv-head

    const float scale = 0.08838834764831845f;  // 1/sqrt(128)
    const float LOG2E = 1.44269504f;

    auto stage_kv = [&](int buf, int k0s) {
#pragma unroll
        for (int it = 0; it < 2; ++it) {
            int id = tid + it * 512;
            int row = id >> 4, slot = id & 15;
            int c8 = ((slot ^ (row & 7)) << 3);
            __builtin_amdgcn_global_load_lds(
                AS1C(Kg + (size_t)(k0s + row) * KVDIM + kvh * HD + c8),
                AS3(Ks[buf] + (size_t)(it * 512 + wave * 64) * 8), 16, 0, 0);
        }
#pragma unroll
        for (int it = 0; it < 2; ++it) {
            int id = tid + it * 512;
            int d = id >> 3, slot = id & 7;
            int c8 = ((slot ^ (d & 7)) << 3);
            __builtin_amdgcn_global_load_lds(
                AS1C(Vh + (size_t)d * SEQ + k0s + c8),
                AS3(Vt[buf] + (size_t)(it * 512 + wave * 64) * 8), 16, 0, 0);
        }
    };

    int g = 0;   // global tile counter (LDS buffer parity)
    for (int half = 0; half < 2; ++half) {
        const int qt = half ? (15 - pairid) : pairid;
        const int q0 = qt * 128;
        const int nkt = 2 * qt + 2;

        // ---- q-tile prologue: stage Q, (first half: also stage tile 0) ----
#pragma unroll
        for (int it = 0; it < 4; ++it) {
            int id = tid + it * 512;
            int row = id >> 4, slot = id & 15;
            int c8 = ((slot ^ (row & 7)) << 3);
            __builtin_amdgcn_global_load_lds(
                AS1C(Q + (size_t)(q0 + row) * DIM + head * HD + c8),
                AS3(Qs + (size_t)(it * 512 + wave * 64) * 8), 16, 0, 0);
        }
        if (half == 0) stage_kv(0, 0);
        __syncthreads();   // Q (and prefetched tile) visible

        bf16x8 qf[4];
#pragma unroll
        for (int ks = 0; ks < 4; ++ks) {
            int r = wave * 16 + l16;
            int slot = (ks * 4 + quad) ^ (r & 7);
            qf[ks] = *(const bf16x8*)(Qs + r * 128 + slot * 8);
        }

        floatx4 acc_o[8] = {};
        float m_run[4], l_run[4];
#pragma unroll
        for (int i = 0; i < 4; ++i) { m_run[i] = -__builtin_inff(); l_run[i] = 0.f; }

        for (int t = 0; t < nkt; ++t, ++g) {
            const int k0 = t * 64;
            const bool diag = (t >= 2 * qt);
            const int cur = g & 1;

            // prefetch next tile (possibly the other half's tile 0)
            if (!(half == 1 && t == nkt - 1)) {
                int k0n = (t + 1 < nkt) ? (t + 1) * 64 : 0;
                stage_kv((g + 1) & 1, k0n);
            }
            __builtin_amdgcn_sched_barrier(0);   // pin prefetch issue early

            // S = Q K^T
            floatx4 acc_s[4] = {};
            __builtin_amdgcn_s_setprio(1);
#pragma unroll
            for (int ks = 0; ks < 4; ++ks) {
                bf16x8 kf[4];
#pragma unroll
                for (int ni = 0; ni < 4; ++ni) {
                    int r = ni * 16 + l16;
                    int slot = (ks * 4 + quad) ^ (r & 7);
                    kf[ni] = *(const bf16x8*)(Ks[cur] + r * 128 + slot * 8);
                }
#pragma unroll
                for (int ni = 0; ni < 4; ++ni)
                    acc_s[ni] = __builtin_amdgcn_mfma_f32_16x16x32_bf16(
                        qf[ks], kf[ni], acc_s[ni], 0, 0, 0);
            }
            __builtin_amdgcn_s_setprio(0);

            // scale + causal mask
#pragma unroll
            for (int ni = 0; ni < 4; ++ni)
#pragma unroll
                for (int i = 0; i < 4; ++i) {
                    float s = acc_s[ni][i] * scale;
                    if (diag) {
                        int ql = q0 + wave * 16 + quad * 4 + i;
                        int kl = k0 + ni * 16 + l16;
                        if (kl > ql) s = -__builtin_inff();
                    }
                    acc_s[ni][i] = s;
                }

            // wave-local online softmax; write P (bf16) into wave-owned rows
            float alpha[4];
#pragma unroll
            for (int i = 0; i < 4; ++i) {
                float v = fmaxf(fmaxf(acc_s[0][i], acc_s[1][i]),
                                fmaxf(acc_s[2][i], acc_s[3][i]));
#pragma unroll
                for (int off = 1; off < 16; off <<= 1)
                    v = fmaxf(v, __shfl_xor(v, off));
                float mn = fmaxf(m_run[i], v);
                alpha[i] = exp2f((m_run[i] - mn) * LOG2E);
                m_run[i] = mn;

                int ql = wave * 16 + quad * 4 + i;
                float sum = 0.f;
#pragma unroll
                for (int ni = 0; ni < 4; ++ni) {
                    float p = exp2f((acc_s[ni][i] - mn) * LOG2E);
                    sum += p;
                    int key = ni * 16 + l16;
                    int slot = ((key >> 3) ^ (ql & 7) ^ ((ql >> 3) & 7)) & 7;
                    Pb[ql * 64 + slot * 8 + (key & 7)] = f2b(p);
                }
#pragma unroll
                for (int off = 1; off < 16; off <<= 1)
                    sum += __shfl_xor(sum, off);
                l_run[i] = l_run[i] * alpha[i] + sum;
            }

            // rescale O accumulator
#pragma unroll
            for (int ni = 0; ni < 8; ++ni)
#pragma unroll
                for (int i = 0; i < 4; ++i)
                    acc_o[ni][i] *= alpha[i];

            // O += P V  (P rows wave-exclusive: same-wave DS order suffices)
            __builtin_amdgcn_s_setprio(1);
#pragma unroll
            for (int ks2 = 0; ks2 < 2; ++ks2) {
                bf16x8 pf, vf[8];
                {
                    int r = wave * 16 + l16;
                    int slot = ((ks2 * 4 + quad) ^ (r & 7) ^ ((r >> 3) & 7)) & 7;
                    pf = *(const bf16x8*)(Pb + r * 64 + slot * 8);
                }
#pragma unroll
                for (int ni = 0; ni < 8; ++ni) {
                    int d = ni * 16 + l16;
                    int slot = ((ks2 * 4 + quad) ^ (d & 7)) & 7;
                    vf[ni] = *(const bf16x8*)(Vt[cur] + d * 64 + slot * 8);
                }
#pragma unroll
                for (int ni = 0; ni < 8; ++ni)
                    acc_o[ni] = __builtin_amdgcn_mfma_f32_16x16x32_bf16(
                        pf, vf[ni], acc_o[ni], 0, 0, 0);
            }
            __builtin_amdgcn_s_setprio(0);

            __syncthreads();   // drains prefetch (vmcnt) + all LDS; next tile ready
        }

        // ---- epilogue for this q-tile ----
#pragma unroll
        for (int i = 0; i < 4; ++i) {
            float inv = 1.0f / l_run[i];
            int row = q0 + wave * 16 + quad * 4 + i;
#pragma unroll
            for (int ni = 0; ni < 8; ++ni) {
                int col = head * HD + ni * 16 + l16;
                O[(size_t)row * DIM + col] = f2b(acc_o[ni][i] * inv);
            }
        }
    }
}

extern "C" void kernel_launch(void* const* d_in, const int* in_sizes, int n_in,
                              void* d_out, int out_size, void* d_ws, size_t ws_size,
                              hipStream_t stream) {
    const void* x  = d_in[0];
    const void* wq = d_in[1];
    const void* wk = d_in[2];
    const void* wv = d_in[3];
    const void* wo = d_in[4];

    // fast-path ws layout (aliased, stream-ordered):
    //   [flag 256B][Kb 4M][VbT 4M][xb 16M][BIG 48M]
    //   BIG = Wqkv[6144][4096] during QKV gemm;
    //   then Ab = BIG[0:16M] (attn out), Wo = BIG+16M (wo bf16, 32M).
    int* flag = (int*)d_ws;
    uint16_t* Kb  = (uint16_t*)((char*)d_ws + 256);
    uint16_t* VbT = Kb + (size_t)SEQ * KVDIM;       // V^T: [KVDIM][SEQ]
    uint16_t* xb  = VbT + (size_t)SEQ * KVDIM;
    uint16_t* BIG = xb + (size_t)SEQ * DIM;
    uint16_t* Wqkv = BIG;
    uint16_t* Ab   = BIG;
    uint16_t* Wo   = BIG + (size_t)SEQ * DIM;
    // Q lives in d_out (dead before the final GEMM overwrites d_out)
    uint16_t* Qb = (uint16_t*)d_out;

    const size_t need = 256 + ((size_t)2 * SEQ * KVDIM     // Kb + VbT
                             + (size_t)SEQ * DIM           // xb
                             + (size_t)QKVDIM * DIM) * 2;  // BIG

    dim3 blk(256);
    detect_k<<<1, blk, 0, stream>>>((const uint16_t*)x, flag);

    if (ws_size >= need) {
        // fast path: pre-convert to bf16, fused QKV gemm, global_load_lds
        conv_k<<<2048, blk, 0, stream>>>(x, xb, (size_t)SEQ * DIM, flag);
        conv_k<<<2048, blk, 0, stream>>>(wq, Wqkv, (size_t)DIM * DIM, flag);
        conv_k<<<2048, blk, 0, stream>>>(wk, Wqkv + (size_t)DIM * DIM,
                                         (size_t)KVDIM * DIM, flag);
        conv_k<<<2048, blk, 0, stream>>>(wv, Wqkv + (size_t)(DIM + KVDIM) * DIM,
                                         (size_t)KVDIM * DIM, flag);
        gemm_qkv<<<dim3(SEQ / 128, QKVDIM / 128), blk, 0, stream>>>(
            xb, Wqkv, Qb, Kb, VbT);
        // Wqkv dead; Wo region (BIG+16M) safe to fill now
        conv_k<<<2048, blk, 0, stream>>>(wo, Wo, (size_t)DIM * DIM, flag);
        rope_k<<<(SEQ * NH * 64) / 256, 256, 0, stream>>>(Qb, NH);
        rope_k<<<(SEQ * NKV * 64) / 256, 256, 0, stream>>>(Kb, NKV);
        attn_k<<<NH * 8, dim3(512), 0, stream>>>(Qb, Kb, VbT, Ab);   // Ab = BIG[0:16M]
        gemm_bf<<<dim3(SEQ / 128, DIM / 128), blk, 0, stream>>>(Ab, Wo, d_out, DIM, DIM, flag, 1);
    } else {
        // legacy path: dynamic-dtype GEMMs, no extra workspace
        uint16_t* AbL = xb;   // legacy Ab right after VbT (within 'fixed' size)
        gemm_nt<<<dim3(SEQ / 128, DIM / 128), blk, 0, stream>>>(x, wq, Qb, DIM, DIM, flag, 1, 1, 0, 0);
        gemm_nt<<<dim3(SEQ / 128, KVDIM / 128), blk, 0, stream>>>(x, wk, Kb, DIM, KVDIM, flag, 1, 1, 0, 0);
        gemm_nt<<<dim3(SEQ / 128, KVDIM / 128), blk, 0, stream>>>(x, wv, VbT, DIM, SEQ, flag, 1, 1, 0, 1);
        rope_k<<<(SEQ * NH * 64) / 256, 256, 0, stream>>>(Qb, NH);
        rope_k<<<(SEQ * NKV * 64) / 256, 256, 0, stream>>>(Kb, NKV);
        attn_k<<<NH * 8, dim3(512), 0, stream>>>(Qb, Kb, VbT, AbL);
        gemm_nt<<<dim3(SEQ / 128, DIM / 128), blk, 0, stream>>>(AbL, wo, d_out, DIM, DIM, flag, 0, 1, 1, 0);
    }
}